// Round 1
// baseline (588.406 us; speedup 1.0000x reference)
//
#include <hip/hip_runtime.h>

#define N_NODES_DEF 50000
#define N_EDGES_DEF 800000

// ---------------------------------------------------------------------------
// CSR build kernels (incoming-edge CSR, built once per launch)
// ---------------------------------------------------------------------------

__global__ void count_k(const int* __restrict__ dst, int* __restrict__ cnt, int e) {
    int i = blockIdx.x * blockDim.x + threadIdx.x;
    if (i < e) atomicAdd(&cnt[dst[i]], 1);
}

// 98 blocks x 256 threads, 512 counts per block -> bsum[b]
__global__ void block_sums(const int* __restrict__ cnt, int* __restrict__ bsum, int n) {
    int b = blockIdx.x, t = threadIdx.x;
    int i0 = b * 512 + 2 * t;
    int s = 0;
    if (i0     < n) s += cnt[i0];
    if (i0 + 1 < n) s += cnt[i0 + 1];
    for (int off = 1; off < 64; off <<= 1) s += __shfl_xor(s, off);
    __shared__ int ws4[4];
    if ((t & 63) == 0) ws4[t >> 6] = s;
    __syncthreads();
    if (t == 0) bsum[b] = ws4[0] + ws4[1] + ws4[2] + ws4[3];
}

// single wave: exclusive-scan bsum[nb] in place (nb <= 128), write rowp[n]=total
__global__ void scan_partials(int* __restrict__ bsum, int* __restrict__ rowp, int nb, int n) {
    int l = threadIdx.x;  // 64 threads
    int v0 = (2 * l     < nb) ? bsum[2 * l]     : 0;
    int v1 = (2 * l + 1 < nb) ? bsum[2 * l + 1] : 0;
    int s = v0 + v1;
    for (int off = 1; off < 64; off <<= 1) {
        int t = __shfl_up(s, off);
        if (l >= off) s += t;
    }
    int excl = s - (v0 + v1);
    if (2 * l     < nb) bsum[2 * l]     = excl;
    if (2 * l + 1 < nb) bsum[2 * l + 1] = excl + v0;
    if (l == 63) rowp[n] = s;  // total edge count
}

// 98 blocks x 256 threads: exclusive scan within 512-chunk + block offset
__global__ void scan_blocks(const int* __restrict__ cnt, const int* __restrict__ bsum,
                            int* __restrict__ rowp, int n) {
    int b = blockIdx.x, t = threadIdx.x;
    int i0 = b * 512 + 2 * t, i1 = i0 + 1;
    int a0 = (i0 < n) ? cnt[i0] : 0;
    int a1 = (i1 < n) ? cnt[i1] : 0;
    int s = a0 + a1;
    int lane = t & 63, w = t >> 6;
    int incl = s;
    for (int off = 1; off < 64; off <<= 1) {
        int tt = __shfl_up(incl, off);
        if (lane >= off) incl += tt;
    }
    __shared__ int wsum[4];
    if (lane == 63) wsum[w] = incl;
    __syncthreads();
    int wpre = 0;
    for (int i = 0; i < w; ++i) wpre += wsum[i];
    int excl = wpre + incl - s + bsum[b];
    if (i0 < n) rowp[i0] = excl;
    if (i1 < n) rowp[i1] = excl + a0;
}

__global__ void fill_k(const int* __restrict__ src, const int* __restrict__ dst,
                       const int* __restrict__ rowp, int* __restrict__ cursor,
                       int* __restrict__ csrc, int e) {
    int i = blockIdx.x * blockDim.x + threadIdx.x;
    if (i < e) {
        int d = dst[i];
        int p = atomicAdd(&cursor[d], 1);
        csrc[rowp[d] + p] = src[i];
    }
}

// ---------------------------------------------------------------------------
// Dual linear: fs = x@Ws + bs, fd = x@Wd + bd.  x is [n,128]; W is [128,COLS].
// 256 threads; thread tile 8 rows x 4 cols per matrix; LDS-staged.
// ---------------------------------------------------------------------------

template <int COLS>
__global__ __launch_bounds__(256) void linear_dual(
    const float* __restrict__ x,
    const float* __restrict__ Wsrc, const float* __restrict__ bsrc,
    const float* __restrict__ Wdst, const float* __restrict__ bdst,
    float* __restrict__ fs, float* __restrict__ fd, int n) {
    constexpr int TC   = COLS / 4;   // col groups (32 or 8)
    constexpr int TR   = 256 / TC;   // row groups (8 or 32)
    constexpr int ROWS = TR * 8;     // 64 or 256
    constexpr int KT   = 32;
    constexpr int XSTR = ROWS + 4;   // pad, multiple of 4 for b128 alignment

    __shared__ float xT[KT][XSTR];
    __shared__ float Wls[KT][COLS];
    __shared__ float Wld[KT][COLS];

    int tid = threadIdx.x;
    int tc = tid % TC, tr = tid / TC;
    int r0 = blockIdx.x * ROWS;

    float accS[8][4];
    float accD[8][4];
#pragma unroll
    for (int r = 0; r < 8; ++r)
#pragma unroll
        for (int j = 0; j < 4; ++j) { accS[r][j] = 0.f; accD[r][j] = 0.f; }

    for (int k0 = 0; k0 < 128; k0 += KT) {
        __syncthreads();
        // stage x chunk transposed: ROWS x KT
        for (int t = tid; t < ROWS * 8; t += 256) {
            int r = t >> 3, k4 = (t & 7) * 4;
            float4 v = make_float4(0.f, 0.f, 0.f, 0.f);
            if (r0 + r < n) v = *(const float4*)(x + (size_t)(r0 + r) * 128 + k0 + k4);
            xT[k4 + 0][r] = v.x; xT[k4 + 1][r] = v.y;
            xT[k4 + 2][r] = v.z; xT[k4 + 3][r] = v.w;
        }
        // stage W chunks: KT x COLS each
        for (int t = tid; t < KT * COLS / 4; t += 256) {
            int k = (t * 4) / COLS, c = (t * 4) % COLS;
            *(float4*)&Wls[k][c] = *(const float4*)(Wsrc + (size_t)(k0 + k) * COLS + c);
            *(float4*)&Wld[k][c] = *(const float4*)(Wdst + (size_t)(k0 + k) * COLS + c);
        }
        __syncthreads();
#pragma unroll 4
        for (int k = 0; k < KT; ++k) {
            float4 xa = *(const float4*)&xT[k][tr * 8];
            float4 xb = *(const float4*)&xT[k][tr * 8 + 4];
            float4 ws = *(const float4*)&Wls[k][tc * 4];
            float4 wd = *(const float4*)&Wld[k][tc * 4];
            float xv[8] = {xa.x, xa.y, xa.z, xa.w, xb.x, xb.y, xb.z, xb.w};
            float wsv[4] = {ws.x, ws.y, ws.z, ws.w};
            float wdv[4] = {wd.x, wd.y, wd.z, wd.w};
#pragma unroll
            for (int r = 0; r < 8; ++r)
#pragma unroll
                for (int j = 0; j < 4; ++j) {
                    accS[r][j] += xv[r] * wsv[j];
                    accD[r][j] += xv[r] * wdv[j];
                }
        }
    }

    float4 bS = *(const float4*)(bsrc + tc * 4);
    float4 bD = *(const float4*)(bdst + tc * 4);
#pragma unroll
    for (int r = 0; r < 8; ++r) {
        int row = r0 + tr * 8 + r;
        if (row < n) {
            float4 o;
            o.x = accS[r][0] + bS.x; o.y = accS[r][1] + bS.y;
            o.z = accS[r][2] + bS.z; o.w = accS[r][3] + bS.w;
            *(float4*)(fs + (size_t)row * COLS + tc * 4) = o;
            o.x = accD[r][0] + bD.x; o.y = accD[r][1] + bD.y;
            o.z = accD[r][2] + bD.z; o.w = accD[r][3] + bD.w;
            *(float4*)(fd + (size_t)row * COLS + tc * 4) = o;
        }
    }
}

// ---------------------------------------------------------------------------
// GATv2 aggregation, dst-centric, one wave per node.
// Layers 0/1: 4 heads x 32 feats (128). Fused LeakyReLU+softmax+agg+ReLU.
// No max-subtraction: logits are O(0.3), exp cannot overflow; identical math.
// ---------------------------------------------------------------------------

__global__ __launch_bounds__(256) void conv128(
    const float* __restrict__ fs, const float* __restrict__ fd,
    const float* __restrict__ attn, const int* __restrict__ rowp,
    const int* __restrict__ csrc, float* __restrict__ out, int n) {
    int wid = blockIdx.x * (blockDim.x >> 6) + (threadIdx.x >> 6);
    if (wid >= n) return;
    int lane = threadIdx.x & 63;
    int f2 = lane * 2;  // features f2, f2+1; head = lane/16
    float2 fdv = *(const float2*)(fd + (size_t)wid * 128 + f2);
    float2 av  = *(const float2*)(attn + f2);
    int rs = rowp[wid], re = rowp[wid + 1];
    float acc0 = 0.f, acc1 = 0.f, denom = 0.f;
    for (int i = rs; i < re; ++i) {
        int s = csrc[i];
        float2 fsv = *(const float2*)(fs + (size_t)s * 128 + f2);
        float e0 = fsv.x + fdv.x;
        float e1 = fsv.y + fdv.y;
        e0 = fmaxf(e0, 0.f) + 0.2f * fminf(e0, 0.f);
        e1 = fmaxf(e1, 0.f) + 0.2f * fminf(e1, 0.f);
        float p = e0 * av.x + e1 * av.y;
        // reduce within 16-lane head group
        p += __shfl_xor(p, 1);
        p += __shfl_xor(p, 2);
        p += __shfl_xor(p, 4);
        p += __shfl_xor(p, 8);
        float ex = __expf(p);
        denom += ex;
        acc0 += ex * fsv.x;
        acc1 += ex * fsv.y;
    }
    float r0 = (re > rs) ? acc0 / denom : 0.f;
    float r1 = (re > rs) ? acc1 / denom : 0.f;
    r0 = fmaxf(r0, 0.f);  // fused inter-layer ReLU
    r1 = fmaxf(r1, 0.f);
    *(float2*)(out + (size_t)wid * 128 + f2) = make_float2(r0, r1);
}

// Layer 2: 1 head x 32 feats. Two edges in flight per wave (32 lanes each).
__global__ __launch_bounds__(256) void conv32(
    const float* __restrict__ fs, const float* __restrict__ fd,
    const float* __restrict__ attn, const int* __restrict__ rowp,
    const int* __restrict__ csrc, float* __restrict__ out, int n) {
    int wid = blockIdx.x * (blockDim.x >> 6) + (threadIdx.x >> 6);
    if (wid >= n) return;
    int lane = threadIdx.x & 63;
    int f = lane & 31, slot = lane >> 5;
    float fdv = fd[(size_t)wid * 32 + f];
    float av  = attn[f];
    int rs = rowp[wid], re = rowp[wid + 1];
    float acc = 0.f, denom = 0.f;
    for (int i = rs + slot; i < re; i += 2) {
        int s = csrc[i];
        float fsv = fs[(size_t)s * 32 + f];
        float e = fsv + fdv;
        e = fmaxf(e, 0.f) + 0.2f * fminf(e, 0.f);
        float p = e * av;
        p += __shfl_xor(p, 1);
        p += __shfl_xor(p, 2);
        p += __shfl_xor(p, 4);
        p += __shfl_xor(p, 8);
        p += __shfl_xor(p, 16);
        float ex = __expf(p);
        denom += ex;
        acc += ex * fsv;
    }
    acc   += __shfl_xor(acc, 32);
    denom += __shfl_xor(denom, 32);
    if (slot == 0)
        out[(size_t)wid * 32 + f] = (re > rs) ? acc / denom : 0.f;
}

// ---------------------------------------------------------------------------

extern "C" void kernel_launch(void* const* d_in, const int* in_sizes, int n_in,
                              void* d_out, int out_size, void* d_ws, size_t ws_size,
                              hipStream_t stream) {
    const float* feats = (const float*)d_in[0];
    const int*   src   = (const int*)d_in[1];
    const int*   dst   = (const int*)d_in[2];
    const float* Ws0 = (const float*)d_in[3],  *bs0 = (const float*)d_in[4];
    const float* Wd0 = (const float*)d_in[5],  *bd0 = (const float*)d_in[6];
    const float* a0  = (const float*)d_in[7];
    const float* Ws1 = (const float*)d_in[8],  *bs1 = (const float*)d_in[9];
    const float* Wd1 = (const float*)d_in[10], *bd1 = (const float*)d_in[11];
    const float* a1  = (const float*)d_in[12];
    const float* Ws2 = (const float*)d_in[13], *bs2 = (const float*)d_in[14];
    const float* Wd2 = (const float*)d_in[15], *bd2 = (const float*)d_in[16];
    const float* a2  = (const float*)d_in[17];

    const int N = in_sizes[0] / 128;  // 50000
    const int E = in_sizes[1];        // 800000

    // workspace layout (bytes, 256-aligned chunks)
    char* ws = (char*)d_ws;
    const size_t featB = (size_t)N * 128 * 4;        // 25.6 MB
    float* fs   = (float*)(ws);
    float* fd   = (float*)(ws + featB);
    float* h    = (float*)(ws + 2 * featB);
    char*  p    = ws + 3 * featB;
    int* rowp   = (int*)p;            p += ((size_t)(N + 1) * 4 + 255) / 256 * 256;
    int* cnt    = (int*)p;            p += ((size_t)N * 4 + 255) / 256 * 256;
    int* cursor = (int*)p;            p += ((size_t)N * 4 + 255) / 256 * 256;
    int* bsum   = (int*)p;            p += 1024;
    int* csrc   = (int*)p;

    const int NB = (N + 511) / 512;   // 98 scan blocks

    // ---- CSR build (graph is identical across all 3 layers) ----
    hipMemsetAsync(cnt, 0, (size_t)N * 4, stream);
    hipMemsetAsync(cursor, 0, (size_t)N * 4, stream);
    count_k<<<(E + 255) / 256, 256, 0, stream>>>(dst, cnt, E);
    block_sums<<<NB, 256, 0, stream>>>(cnt, bsum, N);
    scan_partials<<<1, 64, 0, stream>>>(bsum, rowp, NB, N);
    scan_blocks<<<NB, 256, 0, stream>>>(cnt, bsum, rowp, N);
    fill_k<<<(E + 255) / 256, 256, 0, stream>>>(src, dst, rowp, cursor, csrc, E);

    const int convGrid = (N + 3) / 4;

    // ---- layer 0 ----
    linear_dual<128><<<(N + 63) / 64, 256, 0, stream>>>(feats, Ws0, bs0, Wd0, bd0, fs, fd, N);
    conv128<<<convGrid, 256, 0, stream>>>(fs, fd, a0, rowp, csrc, h, N);
    // ---- layer 1 ----
    linear_dual<128><<<(N + 63) / 64, 256, 0, stream>>>(h, Ws1, bs1, Wd1, bd1, fs, fd, N);
    conv128<<<convGrid, 256, 0, stream>>>(fs, fd, a1, rowp, csrc, h, N);
    // ---- layer 2 ----
    linear_dual<32><<<(N + 255) / 256, 256, 0, stream>>>(h, Ws2, bs2, Wd2, bd2, fs, fd, N);
    conv32<<<convGrid, 256, 0, stream>>>(fs, fd, a2, rowp, csrc, (float*)d_out, N);
}

// Round 2
// 488.605 us; speedup vs baseline: 1.2043x; 1.2043x over previous
//
#include <hip/hip_runtime.h>

// ---------------------------------------------------------------------------
// CSR build kernels (incoming-edge CSR, built once per launch)
// ---------------------------------------------------------------------------

__global__ void count_k(const int* __restrict__ dst, int* __restrict__ cnt, int e) {
    int i = blockIdx.x * blockDim.x + threadIdx.x;
    if (i < e) atomicAdd(&cnt[dst[i]], 1);
}

__global__ void block_sums(const int* __restrict__ cnt, int* __restrict__ bsum, int n) {
    int b = blockIdx.x, t = threadIdx.x;
    int i0 = b * 512 + 2 * t;
    int s = 0;
    if (i0     < n) s += cnt[i0];
    if (i0 + 1 < n) s += cnt[i0 + 1];
    for (int off = 1; off < 64; off <<= 1) s += __shfl_xor(s, off);
    __shared__ int ws4[4];
    if ((t & 63) == 0) ws4[t >> 6] = s;
    __syncthreads();
    if (t == 0) bsum[b] = ws4[0] + ws4[1] + ws4[2] + ws4[3];
}

__global__ void scan_partials(int* __restrict__ bsum, int* __restrict__ rowp, int nb, int n) {
    int l = threadIdx.x;  // 64 threads
    int v0 = (2 * l     < nb) ? bsum[2 * l]     : 0;
    int v1 = (2 * l + 1 < nb) ? bsum[2 * l + 1] : 0;
    int s = v0 + v1;
    for (int off = 1; off < 64; off <<= 1) {
        int t = __shfl_up(s, off);
        if (l >= off) s += t;
    }
    int excl = s - (v0 + v1);
    if (2 * l     < nb) bsum[2 * l]     = excl;
    if (2 * l + 1 < nb) bsum[2 * l + 1] = excl + v0;
    if (l == 63) rowp[n] = s;
}

__global__ void scan_blocks(const int* __restrict__ cnt, const int* __restrict__ bsum,
                            int* __restrict__ rowp, int n) {
    int b = blockIdx.x, t = threadIdx.x;
    int i0 = b * 512 + 2 * t, i1 = i0 + 1;
    int a0 = (i0 < n) ? cnt[i0] : 0;
    int a1 = (i1 < n) ? cnt[i1] : 0;
    int s = a0 + a1;
    int lane = t & 63, w = t >> 6;
    int incl = s;
    for (int off = 1; off < 64; off <<= 1) {
        int tt = __shfl_up(incl, off);
        if (lane >= off) incl += tt;
    }
    __shared__ int wsum[4];
    if (lane == 63) wsum[w] = incl;
    __syncthreads();
    int wpre = 0;
    for (int i = 0; i < w; ++i) wpre += wsum[i];
    int excl = wpre + incl - s + bsum[b];
    if (i0 < n) rowp[i0] = excl;
    if (i1 < n) rowp[i1] = excl + a0;
}

__global__ void fill_k(const int* __restrict__ src, const int* __restrict__ dst,
                       const int* __restrict__ rowp, int* __restrict__ cursor,
                       int* __restrict__ csrc, int e) {
    int i = blockIdx.x * blockDim.x + threadIdx.x;
    if (i < e) {
        int d = dst[i];
        int p = atomicAdd(&cursor[d], 1);
        csrc[rowp[d] + p] = src[i];
    }
}

// ---------------------------------------------------------------------------
// Dual linear: fs = x@Ws + bs, fd = x@Wd + bd.  x is [n,128]; W is [128,COLS].
// ---------------------------------------------------------------------------

template <int COLS>
__global__ __launch_bounds__(256) void linear_dual(
    const float* __restrict__ x,
    const float* __restrict__ Wsrc, const float* __restrict__ bsrc,
    const float* __restrict__ Wdst, const float* __restrict__ bdst,
    float* __restrict__ fs, float* __restrict__ fd, int n) {
    constexpr int TC   = COLS / 4;
    constexpr int TR   = 256 / TC;
    constexpr int ROWS = TR * 8;
    constexpr int KT   = 32;
    constexpr int XSTR = ROWS + 4;

    __shared__ float xT[KT][XSTR];
    __shared__ float Wls[KT][COLS];
    __shared__ float Wld[KT][COLS];

    int tid = threadIdx.x;
    int tc = tid % TC, tr = tid / TC;
    int r0 = blockIdx.x * ROWS;

    float accS[8][4];
    float accD[8][4];
#pragma unroll
    for (int r = 0; r < 8; ++r)
#pragma unroll
        for (int j = 0; j < 4; ++j) { accS[r][j] = 0.f; accD[r][j] = 0.f; }

    for (int k0 = 0; k0 < 128; k0 += KT) {
        __syncthreads();
        for (int t = tid; t < ROWS * 8; t += 256) {
            int r = t >> 3, k4 = (t & 7) * 4;
            float4 v = make_float4(0.f, 0.f, 0.f, 0.f);
            if (r0 + r < n) v = *(const float4*)(x + (size_t)(r0 + r) * 128 + k0 + k4);
            xT[k4 + 0][r] = v.x; xT[k4 + 1][r] = v.y;
            xT[k4 + 2][r] = v.z; xT[k4 + 3][r] = v.w;
        }
        for (int t = tid; t < KT * COLS / 4; t += 256) {
            int k = (t * 4) / COLS, c = (t * 4) % COLS;
            *(float4*)&Wls[k][c] = *(const float4*)(Wsrc + (size_t)(k0 + k) * COLS + c);
            *(float4*)&Wld[k][c] = *(const float4*)(Wdst + (size_t)(k0 + k) * COLS + c);
        }
        __syncthreads();
#pragma unroll 4
        for (int k = 0; k < KT; ++k) {
            float4 xa = *(const float4*)&xT[k][tr * 8];
            float4 xb = *(const float4*)&xT[k][tr * 8 + 4];
            float4 ws = *(const float4*)&Wls[k][tc * 4];
            float4 wd = *(const float4*)&Wld[k][tc * 4];
            float xv[8] = {xa.x, xa.y, xa.z, xa.w, xb.x, xb.y, xb.z, xb.w};
            float wsv[4] = {ws.x, ws.y, ws.z, ws.w};
            float wdv[4] = {wd.x, wd.y, wd.z, wd.w};
#pragma unroll
            for (int r = 0; r < 8; ++r)
#pragma unroll
                for (int j = 0; j < 4; ++j) {
                    accS[r][j] += xv[r] * wsv[j];
                    accD[r][j] += xv[r] * wdv[j];
                }
        }
    }

    float4 bS = *(const float4*)(bsrc + tc * 4);
    float4 bD = *(const float4*)(bdst + tc * 4);
#pragma unroll
    for (int r = 0; r < 8; ++r) {
        int row = r0 + tr * 8 + r;
        if (row < n) {
            float4 o;
            o.x = accS[r][0] + bS.x; o.y = accS[r][1] + bS.y;
            o.z = accS[r][2] + bS.z; o.w = accS[r][3] + bS.w;
            *(float4*)(fs + (size_t)row * COLS + tc * 4) = o;
            o.x = accD[r][0] + bD.x; o.y = accD[r][1] + bD.y;
            o.z = accD[r][2] + bD.z; o.w = accD[r][3] + bD.w;
            *(float4*)(fd + (size_t)row * COLS + tc * 4) = o;
        }
    }
}

// ---------------------------------------------------------------------------
// GATv2 aggregation, dst-centric, one wave per node, 4 edges in flight.
// Layers 0/1: 4 heads x 32 feats (128 = 2 floats/lane, head = lane/16).
// ---------------------------------------------------------------------------

__global__ __launch_bounds__(256) void conv128(
    const float* __restrict__ fs, const float* __restrict__ fd,
    const float* __restrict__ attn, const int* __restrict__ rowp,
    const int* __restrict__ csrc, float* __restrict__ out, int n) {
    int wid = blockIdx.x * (blockDim.x >> 6) + (threadIdx.x >> 6);
    if (wid >= n) return;
    int lane = threadIdx.x & 63;
    int f2 = lane * 2;
    float2 fdv = *(const float2*)(fd + (size_t)wid * 128 + f2);
    float2 av  = *(const float2*)(attn + f2);
    int rs = rowp[wid], re = rowp[wid + 1];
    float acc0 = 0.f, acc1 = 0.f, denom = 0.f;

    int i = rs;
    // 4 independent gathers in flight per iteration (MLP for latency hiding)
    for (; i + 4 <= re; i += 4) {
        int s0 = csrc[i], s1 = csrc[i + 1], s2 = csrc[i + 2], s3 = csrc[i + 3];
        float2 v0 = *(const float2*)(fs + (size_t)s0 * 128 + f2);
        float2 v1 = *(const float2*)(fs + (size_t)s1 * 128 + f2);
        float2 v2 = *(const float2*)(fs + (size_t)s2 * 128 + f2);
        float2 v3 = *(const float2*)(fs + (size_t)s3 * 128 + f2);
        float2 vv[4] = {v0, v1, v2, v3};
#pragma unroll
        for (int u = 0; u < 4; ++u) {
            float e0 = vv[u].x + fdv.x;
            float e1 = vv[u].y + fdv.y;
            e0 = fmaxf(e0, 0.f) + 0.2f * fminf(e0, 0.f);
            e1 = fmaxf(e1, 0.f) + 0.2f * fminf(e1, 0.f);
            float p = e0 * av.x + e1 * av.y;
            p += __shfl_xor(p, 1);
            p += __shfl_xor(p, 2);
            p += __shfl_xor(p, 4);
            p += __shfl_xor(p, 8);
            float ex = __expf(p);
            denom += ex;
            acc0 += ex * vv[u].x;
            acc1 += ex * vv[u].y;
        }
    }
    for (; i < re; ++i) {
        int s = csrc[i];
        float2 fsv = *(const float2*)(fs + (size_t)s * 128 + f2);
        float e0 = fsv.x + fdv.x;
        float e1 = fsv.y + fdv.y;
        e0 = fmaxf(e0, 0.f) + 0.2f * fminf(e0, 0.f);
        e1 = fmaxf(e1, 0.f) + 0.2f * fminf(e1, 0.f);
        float p = e0 * av.x + e1 * av.y;
        p += __shfl_xor(p, 1);
        p += __shfl_xor(p, 2);
        p += __shfl_xor(p, 4);
        p += __shfl_xor(p, 8);
        float ex = __expf(p);
        denom += ex;
        acc0 += ex * fsv.x;
        acc1 += ex * fsv.y;
    }
    float r0 = (re > rs) ? acc0 / denom : 0.f;
    float r1 = (re > rs) ? acc1 / denom : 0.f;
    r0 = fmaxf(r0, 0.f);  // fused inter-layer ReLU
    r1 = fmaxf(r1, 0.f);
    *(float2*)(out + (size_t)wid * 128 + f2) = make_float2(r0, r1);
}

// Layer 2: 1 head x 32 feats. 2 slots x unroll 2 = 4 edges in flight.
__global__ __launch_bounds__(256) void conv32(
    const float* __restrict__ fs, const float* __restrict__ fd,
    const float* __restrict__ attn, const int* __restrict__ rowp,
    const int* __restrict__ csrc, float* __restrict__ out, int n) {
    int wid = blockIdx.x * (blockDim.x >> 6) + (threadIdx.x >> 6);
    if (wid >= n) return;
    int lane = threadIdx.x & 63;
    int f = lane & 31, slot = lane >> 5;
    float fdv = fd[(size_t)wid * 32 + f];
    float av  = attn[f];
    int rs = rowp[wid], re = rowp[wid + 1];
    float acc = 0.f, denom = 0.f;

    int i = rs + slot;
    for (; i + 2 < re; i += 4) {   // this slot handles i and i+2
        int sA = csrc[i], sB = csrc[i + 2];
        float vA = fs[(size_t)sA * 32 + f];
        float vB = fs[(size_t)sB * 32 + f];
        float fv[2] = {vA, vB};
#pragma unroll
        for (int u = 0; u < 2; ++u) {
            float e = fv[u] + fdv;
            e = fmaxf(e, 0.f) + 0.2f * fminf(e, 0.f);
            float p = e * av;
            p += __shfl_xor(p, 1);
            p += __shfl_xor(p, 2);
            p += __shfl_xor(p, 4);
            p += __shfl_xor(p, 8);
            p += __shfl_xor(p, 16);
            float ex = __expf(p);
            denom += ex;
            acc += ex * fv[u];
        }
    }
    for (; i < re; i += 2) {
        int s = csrc[i];
        float fsv = fs[(size_t)s * 32 + f];
        float e = fsv + fdv;
        e = fmaxf(e, 0.f) + 0.2f * fminf(e, 0.f);
        float p = e * av;
        p += __shfl_xor(p, 1);
        p += __shfl_xor(p, 2);
        p += __shfl_xor(p, 4);
        p += __shfl_xor(p, 8);
        p += __shfl_xor(p, 16);
        float ex = __expf(p);
        denom += ex;
        acc += ex * fsv;
    }
    acc   += __shfl_xor(acc, 32);
    denom += __shfl_xor(denom, 32);
    if (slot == 0)
        out[(size_t)wid * 32 + f] = (re > rs) ? acc / denom : 0.f;
}

// ---------------------------------------------------------------------------

extern "C" void kernel_launch(void* const* d_in, const int* in_sizes, int n_in,
                              void* d_out, int out_size, void* d_ws, size_t ws_size,
                              hipStream_t stream) {
    const float* feats = (const float*)d_in[0];
    const int*   src   = (const int*)d_in[1];
    const int*   dst   = (const int*)d_in[2];
    const float* Ws0 = (const float*)d_in[3],  *bs0 = (const float*)d_in[4];
    const float* Wd0 = (const float*)d_in[5],  *bd0 = (const float*)d_in[6];
    const float* a0  = (const float*)d_in[7];
    const float* Ws1 = (const float*)d_in[8],  *bs1 = (const float*)d_in[9];
    const float* Wd1 = (const float*)d_in[10], *bd1 = (const float*)d_in[11];
    const float* a1  = (const float*)d_in[12];
    const float* Ws2 = (const float*)d_in[13], *bs2 = (const float*)d_in[14];
    const float* Wd2 = (const float*)d_in[15], *bd2 = (const float*)d_in[16];
    const float* a2  = (const float*)d_in[17];

    const int N = in_sizes[0] / 128;  // 50000
    const int E = in_sizes[1];        // 800000

    char* ws = (char*)d_ws;
    const size_t featB = (size_t)N * 128 * 4;
    float* fs   = (float*)(ws);
    float* fd   = (float*)(ws + featB);
    float* h    = (float*)(ws + 2 * featB);
    char*  p    = ws + 3 * featB;
    int* rowp   = (int*)p;            p += ((size_t)(N + 1) * 4 + 255) / 256 * 256;
    int* cnt    = (int*)p;            p += ((size_t)N * 4 + 255) / 256 * 256;
    int* cursor = (int*)p;            p += ((size_t)N * 4 + 255) / 256 * 256;
    int* bsum   = (int*)p;            p += 1024;
    int* csrc   = (int*)p;

    const int NB = (N + 511) / 512;

    hipMemsetAsync(cnt, 0, (size_t)N * 4, stream);
    hipMemsetAsync(cursor, 0, (size_t)N * 4, stream);
    count_k<<<(E + 255) / 256, 256, 0, stream>>>(dst, cnt, E);
    block_sums<<<NB, 256, 0, stream>>>(cnt, bsum, N);
    scan_partials<<<1, 64, 0, stream>>>(bsum, rowp, NB, N);
    scan_blocks<<<NB, 256, 0, stream>>>(cnt, bsum, rowp, N);
    fill_k<<<(E + 255) / 256, 256, 0, stream>>>(src, dst, rowp, cursor, csrc, E);

    const int convGrid = (N + 3) / 4;

    linear_dual<128><<<(N + 63) / 64, 256, 0, stream>>>(feats, Ws0, bs0, Wd0, bd0, fs, fd, N);
    conv128<<<convGrid, 256, 0, stream>>>(fs, fd, a0, rowp, csrc, h, N);
    linear_dual<128><<<(N + 63) / 64, 256, 0, stream>>>(h, Ws1, bs1, Wd1, bd1, fs, fd, N);
    conv128<<<convGrid, 256, 0, stream>>>(fs, fd, a1, rowp, csrc, h, N);
    linear_dual<32><<<(N + 255) / 256, 256, 0, stream>>>(h, Ws2, bs2, Wd2, bd2, fs, fd, N);
    conv32<<<convGrid, 256, 0, stream>>>(fs, fd, a2, rowp, csrc, (float*)d_out, N);
}

// Round 3
// 432.365 us; speedup vs baseline: 1.3609x; 1.1301x over previous
//
#include <hip/hip_runtime.h>

typedef __attribute__((ext_vector_type(8))) short bf16x8;
typedef __attribute__((ext_vector_type(4))) float f32x4;

__device__ __forceinline__ unsigned bf_rn(float f) {
    unsigned u = __float_as_uint(f);
    u += 0x7fffu + ((u >> 16) & 1u);
    return u >> 16;
}
__device__ __forceinline__ float bf_lo(unsigned u) { return __uint_as_float(u << 16); }
__device__ __forceinline__ float bf_hi(unsigned u) { return __uint_as_float(u & 0xffff0000u); }
__device__ __forceinline__ float bf_one(unsigned short v) { return __uint_as_float((unsigned)v << 16); }

// ---------------------------------------------------------------------------
// CSR build (incoming-edge CSR, built once per launch)
// ---------------------------------------------------------------------------

__global__ void count_k(const int* __restrict__ dst, int* __restrict__ cnt, int e) {
    int i = blockIdx.x * blockDim.x + threadIdx.x;
    if (i < e) atomicAdd(&cnt[dst[i]], 1);
}

__global__ void block_sums(const int* __restrict__ cnt, int* __restrict__ bsum, int n) {
    int b = blockIdx.x, t = threadIdx.x;
    int i0 = b * 512 + 2 * t;
    int s = 0;
    if (i0     < n) s += cnt[i0];
    if (i0 + 1 < n) s += cnt[i0 + 1];
    for (int off = 1; off < 64; off <<= 1) s += __shfl_xor(s, off);
    __shared__ int ws4[4];
    if ((t & 63) == 0) ws4[t >> 6] = s;
    __syncthreads();
    if (t == 0) bsum[b] = ws4[0] + ws4[1] + ws4[2] + ws4[3];
}

__global__ void scan_partials(int* __restrict__ bsum, int* __restrict__ rowp, int nb, int n) {
    int l = threadIdx.x;  // 64 threads
    int v0 = (2 * l     < nb) ? bsum[2 * l]     : 0;
    int v1 = (2 * l + 1 < nb) ? bsum[2 * l + 1] : 0;
    int s = v0 + v1;
    for (int off = 1; off < 64; off <<= 1) {
        int t = __shfl_up(s, off);
        if (l >= off) s += t;
    }
    int excl = s - (v0 + v1);
    if (2 * l     < nb) bsum[2 * l]     = excl;
    if (2 * l + 1 < nb) bsum[2 * l + 1] = excl + v0;
    if (l == 63) rowp[n] = s;
}

__global__ void scan_blocks(const int* __restrict__ cnt, const int* __restrict__ bsum,
                            int* __restrict__ rowp, int n) {
    int b = blockIdx.x, t = threadIdx.x;
    int i0 = b * 512 + 2 * t, i1 = i0 + 1;
    int a0 = (i0 < n) ? cnt[i0] : 0;
    int a1 = (i1 < n) ? cnt[i1] : 0;
    int s = a0 + a1;
    int lane = t & 63, w = t >> 6;
    int incl = s;
    for (int off = 1; off < 64; off <<= 1) {
        int tt = __shfl_up(incl, off);
        if (lane >= off) incl += tt;
    }
    __shared__ int wsum[4];
    if (lane == 63) wsum[w] = incl;
    __syncthreads();
    int wpre = 0;
    for (int i = 0; i < w; ++i) wpre += wsum[i];
    int excl = wpre + incl - s + bsum[b];
    if (i0 < n) rowp[i0] = excl;
    if (i1 < n) rowp[i1] = excl + a0;
}

__global__ void fill_k(const int* __restrict__ src, const int* __restrict__ dst,
                       const int* __restrict__ rowp, int* __restrict__ cursor,
                       int* __restrict__ csrc, int e) {
    int i = blockIdx.x * blockDim.x + threadIdx.x;
    if (i < e) {
        int d = dst[i];
        int p = atomicAdd(&cursor[d], 1);
        csrc[rowp[d] + p] = src[i];
    }
}

// ---------------------------------------------------------------------------
// fp32 -> bf16 conversion of the input features (once per launch)
// ---------------------------------------------------------------------------

__global__ void convert_feat(const float* __restrict__ x, unsigned short* __restrict__ o, int n4) {
    int i = blockIdx.x * blockDim.x + threadIdx.x;
    if (i < n4) {
        float4 v = *(const float4*)(x + (size_t)i * 4);
        ushort4 r;
        r.x = (unsigned short)bf_rn(v.x); r.y = (unsigned short)bf_rn(v.y);
        r.z = (unsigned short)bf_rn(v.z); r.w = (unsigned short)bf_rn(v.w);
        *(ushort4*)(o + (size_t)i * 4) = r;
    }
}

// W transpose+convert for all 3 layers in one launch.
// wt[c][k] = (c<C ? Ws[k][c] : Wd[k][c-C]) as bf16; layer0/1: C=128, layer2: C=32.
__global__ void transpose_all(
    const float* __restrict__ Ws0, const float* __restrict__ Wd0,
    const float* __restrict__ Ws1, const float* __restrict__ Wd1,
    const float* __restrict__ Ws2, const float* __restrict__ Wd2,
    unsigned short* __restrict__ wt0, unsigned short* __restrict__ wt1,
    unsigned short* __restrict__ wt2) {
    int gid = blockIdx.x * blockDim.x + threadIdx.x;
    if (gid < 65536) {  // layers 0,1: 256 c-rows x 128 k each
        int l = gid >> 15, loc = gid & 32767;
        int c = loc >> 7, k = loc & 127;
        const float* W = (c < 128) ? (l ? Ws1 : Ws0) : (l ? Wd1 : Wd0);
        int cc = c & 127;
        float v = W[(size_t)k * 128 + cc];
        (l ? wt1 : wt0)[loc] = (unsigned short)bf_rn(v);
    } else if (gid < 65536 + 8192) {  // layer 2: 64 c-rows x 128 k
        int loc = gid - 65536;
        int c = loc >> 7, k = loc & 127;
        const float* W = (c < 32) ? Ws2 : Wd2;
        int cc = (c < 32) ? c : c - 32;
        float v = W[(size_t)k * 32 + cc];
        wt2[loc] = (unsigned short)bf_rn(v);
    }
}

// ---------------------------------------------------------------------------
// MFMA dual GEMM: [fs|fd] = x @ [Ws|Wd] + [bs|bd], bf16 in/out, fp32 acc.
// Block: 256 thr = 4 waves in 2x2 (row-half x col-half). M-tile 128 rows.
// xb: [n][128] bf16 row-major.  wt: [COLS2][128] bf16 (transposed weights).
// A frag: A[m=lane&15][k=quad*8+j]; B frag: B[n=lane&15][k=quad*8+j];
// D: row = quad*4+reg, col = lane&15   [m89/m91 verified layouts]
// ---------------------------------------------------------------------------

template <int COLS2>
__global__ __launch_bounds__(256) void gemm_dual(
    const unsigned short* __restrict__ xb, const unsigned short* __restrict__ wt,
    const float* __restrict__ bs, const float* __restrict__ bd,
    unsigned short* __restrict__ fs, unsigned short* __restrict__ fd, int n) {
    constexpr int C   = COLS2 / 2;
    constexpr int NTW = COLS2 / 32;   // col-tiles per wave (half the cols)
    constexpr int LDK = 136;          // shorts per LDS row (272 B, 16B-aligned pad)

    __shared__ unsigned short xs[128 * LDK];
    __shared__ unsigned short ws[COLS2 * LDK];

    const int tid  = threadIdx.x;
    const int lane = tid & 63, w = tid >> 6;
    const int wr = w & 1, wc = w >> 1;
    const int m = lane & 15, quad = lane >> 4;
    const int r0 = blockIdx.x * 128;

    // stage x tile: 128 rows x 16 chunks of 16B
    for (int t = tid; t < 128 * 16; t += 256) {
        int r = t >> 4, q = t & 15;
        uint4 v = make_uint4(0u, 0u, 0u, 0u);
        if (r0 + r < n) v = *(const uint4*)(xb + (size_t)(r0 + r) * 128 + q * 8);
        *(uint4*)(&xs[r * LDK + q * 8]) = v;
    }
    // stage Wt: COLS2 rows x 16 chunks
    for (int t = tid; t < COLS2 * 16; t += 256) {
        int c = t >> 4, q = t & 15;
        uint4 v = *(const uint4*)(wt + (size_t)c * 128 + q * 8);
        *(uint4*)(&ws[c * LDK + q * 8]) = v;
    }
    __syncthreads();

    f32x4 acc[4][NTW];
#pragma unroll
    for (int rt = 0; rt < 4; ++rt)
#pragma unroll
        for (int ct = 0; ct < NTW; ++ct) acc[rt][ct] = (f32x4){0.f, 0.f, 0.f, 0.f};

#pragma unroll
    for (int ks = 0; ks < 4; ++ks) {
        const int kofs = ks * 32 + quad * 8;
        bf16x8 a[4], b[NTW];
#pragma unroll
        for (int rt = 0; rt < 4; ++rt)
            a[rt] = *(const bf16x8*)(&xs[(wr * 64 + rt * 16 + m) * LDK + kofs]);
#pragma unroll
        for (int ct = 0; ct < NTW; ++ct)
            b[ct] = *(const bf16x8*)(&ws[(wc * (NTW * 16) + ct * 16 + m) * LDK + kofs]);
#pragma unroll
        for (int rt = 0; rt < 4; ++rt)
#pragma unroll
            for (int ct = 0; ct < NTW; ++ct)
                acc[rt][ct] = __builtin_amdgcn_mfma_f32_16x16x32_bf16(a[rt], b[ct], acc[rt][ct], 0, 0, 0);
    }

#pragma unroll
    for (int ct = 0; ct < NTW; ++ct) {
        int col = wc * (NTW * 16) + ct * 16 + m;
        unsigned short* base = (col < C) ? fs : fd;
        int cc = (col < C) ? col : col - C;
        float bias = (col < C) ? bs[cc] : bd[cc];
#pragma unroll
        for (int rt = 0; rt < 4; ++rt) {
            int rbase = r0 + wr * 64 + rt * 16 + quad * 4;
#pragma unroll
            for (int j = 0; j < 4; ++j) {
                int row = rbase + j;
                if (row < n)
                    base[(size_t)row * C + cc] = (unsigned short)bf_rn(acc[rt][ct][j] + bias);
            }
        }
    }
}

// ---------------------------------------------------------------------------
// GATv2 aggregation, dst-centric, one wave per node, 4 edges in flight.
// bf16 feats (4B/lane gathers), fp32 math, bf16 h output.
// ---------------------------------------------------------------------------

__global__ __launch_bounds__(256) void conv128(
    const unsigned short* __restrict__ fs, const unsigned short* __restrict__ fd,
    const float* __restrict__ attn, const int* __restrict__ rowp,
    const int* __restrict__ csrc, unsigned short* __restrict__ out, int n) {
    int wid = blockIdx.x * 4 + (threadIdx.x >> 6);
    if (wid >= n) return;
    int lane = threadIdx.x & 63;
    unsigned ud = ((const unsigned*)(fd + (size_t)wid * 128))[lane];
    float fd0 = bf_lo(ud), fd1 = bf_hi(ud);
    float2 av = *(const float2*)(attn + lane * 2);
    int rs = rowp[wid], re = rowp[wid + 1];
    float acc0 = 0.f, acc1 = 0.f, denom = 0.f;

    int i = rs;
    for (; i + 4 <= re; i += 4) {
        int s0 = csrc[i], s1 = csrc[i + 1], s2 = csrc[i + 2], s3 = csrc[i + 3];
        unsigned u0 = ((const unsigned*)(fs + (size_t)s0 * 128))[lane];
        unsigned u1 = ((const unsigned*)(fs + (size_t)s1 * 128))[lane];
        unsigned u2 = ((const unsigned*)(fs + (size_t)s2 * 128))[lane];
        unsigned u3 = ((const unsigned*)(fs + (size_t)s3 * 128))[lane];
        unsigned uu[4] = {u0, u1, u2, u3};
#pragma unroll
        for (int u = 0; u < 4; ++u) {
            float x0 = bf_lo(uu[u]), x1 = bf_hi(uu[u]);
            float e0 = x0 + fd0, e1 = x1 + fd1;
            e0 = fmaxf(e0, 0.f) + 0.2f * fminf(e0, 0.f);
            e1 = fmaxf(e1, 0.f) + 0.2f * fminf(e1, 0.f);
            float p = e0 * av.x + e1 * av.y;
            p += __shfl_xor(p, 1);
            p += __shfl_xor(p, 2);
            p += __shfl_xor(p, 4);
            p += __shfl_xor(p, 8);
            float ex = __expf(p);
            denom += ex;
            acc0 += ex * x0;
            acc1 += ex * x1;
        }
    }
    for (; i < re; ++i) {
        int s = csrc[i];
        unsigned u = ((const unsigned*)(fs + (size_t)s * 128))[lane];
        float x0 = bf_lo(u), x1 = bf_hi(u);
        float e0 = x0 + fd0, e1 = x1 + fd1;
        e0 = fmaxf(e0, 0.f) + 0.2f * fminf(e0, 0.f);
        e1 = fmaxf(e1, 0.f) + 0.2f * fminf(e1, 0.f);
        float p = e0 * av.x + e1 * av.y;
        p += __shfl_xor(p, 1);
        p += __shfl_xor(p, 2);
        p += __shfl_xor(p, 4);
        p += __shfl_xor(p, 8);
        float ex = __expf(p);
        denom += ex;
        acc0 += ex * x0;
        acc1 += ex * x1;
    }
    float inv = (re > rs) ? 1.f / denom : 0.f;
    float r0 = fmaxf(acc0 * inv, 0.f);  // fused inter-layer ReLU
    float r1 = fmaxf(acc1 * inv, 0.f);
    ((unsigned*)(out + (size_t)wid * 128))[lane] = (bf_rn(r1) << 16) | bf_rn(r0);
}

// Layer 2: 1 head x 32 feats, bf16 in, fp32 out. 2 slots x unroll 2.
__global__ __launch_bounds__(256) void conv32(
    const unsigned short* __restrict__ fs, const unsigned short* __restrict__ fd,
    const float* __restrict__ attn, const int* __restrict__ rowp,
    const int* __restrict__ csrc, float* __restrict__ out, int n) {
    int wid = blockIdx.x * 4 + (threadIdx.x >> 6);
    if (wid >= n) return;
    int lane = threadIdx.x & 63;
    int f = lane & 31, slot = lane >> 5;
    float fdv = bf_one(fd[(size_t)wid * 32 + f]);
    float av  = attn[f];
    int rs = rowp[wid], re = rowp[wid + 1];
    float acc = 0.f, denom = 0.f;

    int i = rs + slot;
    for (; i + 2 < re; i += 4) {
        int sA = csrc[i], sB = csrc[i + 2];
        float vA = bf_one(fs[(size_t)sA * 32 + f]);
        float vB = bf_one(fs[(size_t)sB * 32 + f]);
        float fv[2] = {vA, vB};
#pragma unroll
        for (int u = 0; u < 2; ++u) {
            float e = fv[u] + fdv;
            e = fmaxf(e, 0.f) + 0.2f * fminf(e, 0.f);
            float p = e * av;
            p += __shfl_xor(p, 1);
            p += __shfl_xor(p, 2);
            p += __shfl_xor(p, 4);
            p += __shfl_xor(p, 8);
            p += __shfl_xor(p, 16);
            float ex = __expf(p);
            denom += ex;
            acc += ex * fv[u];
        }
    }
    for (; i < re; i += 2) {
        int s = csrc[i];
        float fsv = bf_one(fs[(size_t)s * 32 + f]);
        float e = fsv + fdv;
        e = fmaxf(e, 0.f) + 0.2f * fminf(e, 0.f);
        float p = e * av;
        p += __shfl_xor(p, 1);
        p += __shfl_xor(p, 2);
        p += __shfl_xor(p, 4);
        p += __shfl_xor(p, 8);
        p += __shfl_xor(p, 16);
        float ex = __expf(p);
        denom += ex;
        acc += ex * fsv;
    }
    acc   += __shfl_xor(acc, 32);
    denom += __shfl_xor(denom, 32);
    if (slot == 0)
        out[(size_t)wid * 32 + f] = (re > rs) ? acc / denom : 0.f;
}

// ---------------------------------------------------------------------------

extern "C" void kernel_launch(void* const* d_in, const int* in_sizes, int n_in,
                              void* d_out, int out_size, void* d_ws, size_t ws_size,
                              hipStream_t stream) {
    const float* feats = (const float*)d_in[0];
    const int*   src   = (const int*)d_in[1];
    const int*   dst   = (const int*)d_in[2];
    const float* Ws0 = (const float*)d_in[3],  *bs0 = (const float*)d_in[4];
    const float* Wd0 = (const float*)d_in[5],  *bd0 = (const float*)d_in[6];
    const float* a0  = (const float*)d_in[7];
    const float* Ws1 = (const float*)d_in[8],  *bs1 = (const float*)d_in[9];
    const float* Wd1 = (const float*)d_in[10], *bd1 = (const float*)d_in[11];
    const float* a1  = (const float*)d_in[12];
    const float* Ws2 = (const float*)d_in[13], *bs2 = (const float*)d_in[14];
    const float* Wd2 = (const float*)d_in[15], *bd2 = (const float*)d_in[16];
    const float* a2  = (const float*)d_in[17];

    const int N = in_sizes[0] / 128;  // 50000
    const int E = in_sizes[1];        // 800000

    char* ws = (char*)d_ws;
    const size_t featB = (size_t)N * 128 * 2;  // 12.8 MB (bf16)
    unsigned short* xb  = (unsigned short*)(ws);
    unsigned short* hb  = (unsigned short*)(ws + featB);
    unsigned short* fsb = (unsigned short*)(ws + 2 * featB);
    unsigned short* fdb = (unsigned short*)(ws + 3 * featB);
    char* p = ws + 4 * featB;
    unsigned short* wt0 = (unsigned short*)p; p += 256 * 128 * 2;
    unsigned short* wt1 = (unsigned short*)p; p += 256 * 128 * 2;
    unsigned short* wt2 = (unsigned short*)p; p += 64 * 128 * 2;
    int* rowp   = (int*)p;  p += ((size_t)(N + 1) * 4 + 255) / 256 * 256;
    int* cnt    = (int*)p;  p += ((size_t)N * 4 + 255) / 256 * 256;
    int* cursor = (int*)p;  p += ((size_t)N * 4 + 255) / 256 * 256;
    int* bsum   = (int*)p;  p += 1024;
    int* csrc   = (int*)p;

    const int NB = (N + 511) / 512;

    // ---- CSR build ----
    hipMemsetAsync(cnt, 0, (size_t)N * 4, stream);
    hipMemsetAsync(cursor, 0, (size_t)N * 4, stream);
    count_k<<<(E + 255) / 256, 256, 0, stream>>>(dst, cnt, E);
    block_sums<<<NB, 256, 0, stream>>>(cnt, bsum, N);
    scan_partials<<<1, 64, 0, stream>>>(bsum, rowp, NB, N);
    scan_blocks<<<NB, 256, 0, stream>>>(cnt, bsum, rowp, N);
    fill_k<<<(E + 255) / 256, 256, 0, stream>>>(src, dst, rowp, cursor, csrc, E);

    // ---- bf16 conversions ----
    const int n4 = N * 128 / 4;
    convert_feat<<<(n4 + 255) / 256, 256, 0, stream>>>(feats, xb, n4);
    transpose_all<<<(73728 + 255) / 256, 256, 0, stream>>>(Ws0, Wd0, Ws1, Wd1, Ws2, Wd2, wt0, wt1, wt2);

    const int gemmGrid = (N + 127) / 128;
    const int convGrid = (N + 3) / 4;

    // ---- layer 0 ----
    gemm_dual<256><<<gemmGrid, 256, 0, stream>>>(xb, wt0, bs0, bd0, fsb, fdb, N);
    conv128<<<convGrid, 256, 0, stream>>>(fsb, fdb, a0, rowp, csrc, hb, N);
    // ---- layer 1 ----
    gemm_dual<256><<<gemmGrid, 256, 0, stream>>>(hb, wt1, bs1, bd1, fsb, fdb, N);
    conv128<<<convGrid, 256, 0, stream>>>(fsb, fdb, a1, rowp, csrc, hb, N);
    // ---- layer 2 ----
    gemm_dual<64><<<gemmGrid, 256, 0, stream>>>(hb, wt2, bs2, bd2, fsb, fdb, N);
    conv32<<<convGrid, 256, 0, stream>>>(fsb, fdb, a2, rowp, csrc, (float*)d_out, N);
}

// Round 4
// 418.725 us; speedup vs baseline: 1.4052x; 1.0326x over previous
//
#include <hip/hip_runtime.h>

typedef __attribute__((ext_vector_type(8))) short bf16x8;
typedef __attribute__((ext_vector_type(4))) float f32x4;

#define LOG2E 1.4426950408889634f

__device__ __forceinline__ unsigned bf_rn(float f) {
    unsigned u = __float_as_uint(f);
    u += 0x7fffu + ((u >> 16) & 1u);
    return u >> 16;
}
__device__ __forceinline__ float bf_lo(unsigned u) { return __uint_as_float(u << 16); }
__device__ __forceinline__ float bf_hi(unsigned u) { return __uint_as_float(u & 0xffff0000u); }
__device__ __forceinline__ float bf_one(unsigned short v) { return __uint_as_float((unsigned)v << 16); }

// DPP row-rotate add: cross-lane within 16-lane row on the VALU pipe (no DS).
template <int CTRL>
__device__ __forceinline__ float dpp_radd(float x) {
    int t = __builtin_amdgcn_update_dpp(0, __float_as_int(x), CTRL, 0xF, 0xF, true);
    return x + __int_as_float(t);
}
// full sum across a 16-lane row (all lanes get the sum)
__device__ __forceinline__ float row16_sum(float p) {
    p = dpp_radd<0x128>(p);  // row_ror:8
    p = dpp_radd<0x124>(p);  // row_ror:4
    p = dpp_radd<0x122>(p);  // row_ror:2
    p = dpp_radd<0x121>(p);  // row_ror:1
    return p;
}

__device__ __forceinline__ float fast_exp2(float x) {
#if __has_builtin(__builtin_amdgcn_exp2f)
    return __builtin_amdgcn_exp2f(x);
#else
    return __expf(x * 0.6931471805599453f);
#endif
}

// ---------------------------------------------------------------------------
// CSR build (incoming-edge CSR, built once per launch)
// ---------------------------------------------------------------------------

__global__ void count_k(const int* __restrict__ dst, int* __restrict__ cnt, int e) {
    int i = blockIdx.x * blockDim.x + threadIdx.x;
    if (i < e) atomicAdd(&cnt[dst[i]], 1);
}

__global__ void block_sums(const int* __restrict__ cnt, int* __restrict__ bsum, int n) {
    int b = blockIdx.x, t = threadIdx.x;
    int i0 = b * 512 + 2 * t;
    int s = 0;
    if (i0     < n) s += cnt[i0];
    if (i0 + 1 < n) s += cnt[i0 + 1];
    for (int off = 1; off < 64; off <<= 1) s += __shfl_xor(s, off);
    __shared__ int ws4[4];
    if ((t & 63) == 0) ws4[t >> 6] = s;
    __syncthreads();
    if (t == 0) bsum[b] = ws4[0] + ws4[1] + ws4[2] + ws4[3];
}

__global__ void scan_partials(int* __restrict__ bsum, int* __restrict__ rowp, int nb, int n) {
    int l = threadIdx.x;  // 64 threads
    int v0 = (2 * l     < nb) ? bsum[2 * l]     : 0;
    int v1 = (2 * l + 1 < nb) ? bsum[2 * l + 1] : 0;
    int s = v0 + v1;
    for (int off = 1; off < 64; off <<= 1) {
        int t = __shfl_up(s, off);
        if (l >= off) s += t;
    }
    int excl = s - (v0 + v1);
    if (2 * l     < nb) bsum[2 * l]     = excl;
    if (2 * l + 1 < nb) bsum[2 * l + 1] = excl + v0;
    if (l == 63) rowp[n] = s;
}

__global__ void scan_blocks(const int* __restrict__ cnt, const int* __restrict__ bsum,
                            int* __restrict__ rowp, int n) {
    int b = blockIdx.x, t = threadIdx.x;
    int i0 = b * 512 + 2 * t, i1 = i0 + 1;
    int a0 = (i0 < n) ? cnt[i0] : 0;
    int a1 = (i1 < n) ? cnt[i1] : 0;
    int s = a0 + a1;
    int lane = t & 63, w = t >> 6;
    int incl = s;
    for (int off = 1; off < 64; off <<= 1) {
        int tt = __shfl_up(incl, off);
        if (lane >= off) incl += tt;
    }
    __shared__ int wsum[4];
    if (lane == 63) wsum[w] = incl;
    __syncthreads();
    int wpre = 0;
    for (int i = 0; i < w; ++i) wpre += wsum[i];
    int excl = wpre + incl - s + bsum[b];
    if (i0 < n) rowp[i0] = excl;
    if (i1 < n) rowp[i1] = excl + a0;
}

// cur starts as a copy of rowp (d2d); csrc[pos] gets src node
__global__ void fill_k(const int* __restrict__ src, const int* __restrict__ dst,
                       int* __restrict__ cur, int* __restrict__ csrc, int e) {
    int i = blockIdx.x * blockDim.x + threadIdx.x;
    if (i < e) {
        int pos = atomicAdd(&cur[dst[i]], 1);
        csrc[pos] = src[i];
    }
}

// ---------------------------------------------------------------------------
// fp32 -> bf16 conversions (once per launch)
// ---------------------------------------------------------------------------

__global__ void convert_feat(const float* __restrict__ x, unsigned short* __restrict__ o, int n4) {
    int i = blockIdx.x * blockDim.x + threadIdx.x;
    if (i < n4) {
        float4 v = *(const float4*)(x + (size_t)i * 4);
        ushort4 r;
        r.x = (unsigned short)bf_rn(v.x); r.y = (unsigned short)bf_rn(v.y);
        r.z = (unsigned short)bf_rn(v.z); r.w = (unsigned short)bf_rn(v.w);
        *(ushort4*)(o + (size_t)i * 4) = r;
    }
}

// W transpose+convert for all 3 layers in one launch.
__global__ void transpose_all(
    const float* __restrict__ Ws0, const float* __restrict__ Wd0,
    const float* __restrict__ Ws1, const float* __restrict__ Wd1,
    const float* __restrict__ Ws2, const float* __restrict__ Wd2,
    unsigned short* __restrict__ wt0, unsigned short* __restrict__ wt1,
    unsigned short* __restrict__ wt2) {
    int gid = blockIdx.x * blockDim.x + threadIdx.x;
    if (gid < 65536) {  // layers 0,1: 256 c-rows x 128 k each
        int l = gid >> 15, loc = gid & 32767;
        int c = loc >> 7, k = loc & 127;
        const float* W = (c < 128) ? (l ? Ws1 : Ws0) : (l ? Wd1 : Wd0);
        int cc = c & 127;
        float v = W[(size_t)k * 128 + cc];
        (l ? wt1 : wt0)[loc] = (unsigned short)bf_rn(v);
    } else if (gid < 65536 + 8192) {  // layer 2: 64 c-rows x 128 k
        int loc = gid - 65536;
        int c = loc >> 7, k = loc & 127;
        const float* W = (c < 32) ? Ws2 : Wd2;
        int cc = (c < 32) ? c : c - 32;
        float v = W[(size_t)k * 32 + cc];
        wt2[loc] = (unsigned short)bf_rn(v);
    }
}

// ---------------------------------------------------------------------------
// MFMA dual GEMM: [fs|fd] = x @ [Ws|Wd] + [bs|bd], bf16 in/out, fp32 acc.
// ---------------------------------------------------------------------------

template <int COLS2>
__global__ __launch_bounds__(256) void gemm_dual(
    const unsigned short* __restrict__ xb, const unsigned short* __restrict__ wt,
    const float* __restrict__ bs, const float* __restrict__ bd,
    unsigned short* __restrict__ fs, unsigned short* __restrict__ fd, int n) {
    constexpr int C   = COLS2 / 2;
    constexpr int NTW = COLS2 / 32;
    constexpr int LDK = 136;

    __shared__ unsigned short xs[128 * LDK];
    __shared__ unsigned short ws[COLS2 * LDK];

    const int tid  = threadIdx.x;
    const int lane = tid & 63, w = tid >> 6;
    const int wr = w & 1, wc = w >> 1;
    const int m = lane & 15, quad = lane >> 4;
    const int r0 = blockIdx.x * 128;

    for (int t = tid; t < 128 * 16; t += 256) {
        int r = t >> 4, q = t & 15;
        uint4 v = make_uint4(0u, 0u, 0u, 0u);
        if (r0 + r < n) v = *(const uint4*)(xb + (size_t)(r0 + r) * 128 + q * 8);
        *(uint4*)(&xs[r * LDK + q * 8]) = v;
    }
    for (int t = tid; t < COLS2 * 16; t += 256) {
        int c = t >> 4, q = t & 15;
        uint4 v = *(const uint4*)(wt + (size_t)c * 128 + q * 8);
        *(uint4*)(&ws[c * LDK + q * 8]) = v;
    }
    __syncthreads();

    f32x4 acc[4][NTW];
#pragma unroll
    for (int rt = 0; rt < 4; ++rt)
#pragma unroll
        for (int ct = 0; ct < NTW; ++ct) acc[rt][ct] = (f32x4){0.f, 0.f, 0.f, 0.f};

#pragma unroll
    for (int ks = 0; ks < 4; ++ks) {
        const int kofs = ks * 32 + quad * 8;
        bf16x8 a[4], b[NTW];
#pragma unroll
        for (int rt = 0; rt < 4; ++rt)
            a[rt] = *(const bf16x8*)(&xs[(wr * 64 + rt * 16 + m) * LDK + kofs]);
#pragma unroll
        for (int ct = 0; ct < NTW; ++ct)
            b[ct] = *(const bf16x8*)(&ws[(wc * (NTW * 16) + ct * 16 + m) * LDK + kofs]);
#pragma unroll
        for (int rt = 0; rt < 4; ++rt)
#pragma unroll
            for (int ct = 0; ct < NTW; ++ct)
                acc[rt][ct] = __builtin_amdgcn_mfma_f32_16x16x32_bf16(a[rt], b[ct], acc[rt][ct], 0, 0, 0);
    }

#pragma unroll
    for (int ct = 0; ct < NTW; ++ct) {
        int col = wc * (NTW * 16) + ct * 16 + m;
        unsigned short* base = (col < C) ? fs : fd;
        int cc = (col < C) ? col : col - C;
        float bias = (col < C) ? bs[cc] : bd[cc];
#pragma unroll
        for (int rt = 0; rt < 4; ++rt) {
            int rbase = r0 + wr * 64 + rt * 16 + quad * 4;
#pragma unroll
            for (int j = 0; j < 4; ++j) {
                int row = rbase + j;
                if (row < n)
                    base[(size_t)row * C + cc] = (unsigned short)bf_rn(acc[rt][ct][j] + bias);
            }
        }
    }
}

// ---------------------------------------------------------------------------
// GATv2 aggregation: dst-centric, persistent waves (static node stride),
// DPP row reduction, leaky = 0.6x+0.4|x| with pre-scaled attn, exp2.
// ---------------------------------------------------------------------------

__global__ __launch_bounds__(256) void conv128(
    const unsigned short* __restrict__ fs, const unsigned short* __restrict__ fd,
    const float* __restrict__ attn, const int* __restrict__ rowp,
    const int* __restrict__ csrc, unsigned short* __restrict__ out, int n) {
    const int nwaves = gridDim.x * 4;
    const int wid0 = blockIdx.x * 4 + (threadIdx.x >> 6);
    const int lane = threadIdx.x & 63;

    float2 av = *(const float2*)(attn + lane * 2);
    const float a06x = av.x * 0.6f * LOG2E, a04x = av.x * 0.4f * LOG2E;
    const float a06y = av.y * 0.6f * LOG2E, a04y = av.y * 0.4f * LOG2E;

    for (int wid = wid0; wid < n; wid += nwaves) {
        unsigned ud = ((const unsigned*)(fd + (size_t)wid * 128))[lane];
        float fd0 = bf_lo(ud), fd1 = bf_hi(ud);
        int rs = rowp[wid], re = rowp[wid + 1];
        float acc0 = 0.f, acc1 = 0.f, denom = 0.f;

        int i = rs;
        for (; i + 4 <= re; i += 4) {
            int s0 = csrc[i], s1 = csrc[i + 1], s2 = csrc[i + 2], s3 = csrc[i + 3];
            unsigned u0 = ((const unsigned*)(fs + (size_t)s0 * 128))[lane];
            unsigned u1 = ((const unsigned*)(fs + (size_t)s1 * 128))[lane];
            unsigned u2 = ((const unsigned*)(fs + (size_t)s2 * 128))[lane];
            unsigned u3 = ((const unsigned*)(fs + (size_t)s3 * 128))[lane];
            unsigned uu[4] = {u0, u1, u2, u3};
#pragma unroll
            for (int u = 0; u < 4; ++u) {
                float x0 = bf_lo(uu[u]), x1 = bf_hi(uu[u]);
                float t0 = x0 + fd0, t1 = x1 + fd1;
                float p = a06x * t0;
                p = fmaf(a04x, fabsf(t0), p);
                p = fmaf(a06y, t1, p);
                p = fmaf(a04y, fabsf(t1), p);
                p = row16_sum(p);
                float ex = fast_exp2(p);
                denom += ex;
                acc0 = fmaf(ex, x0, acc0);
                acc1 = fmaf(ex, x1, acc1);
            }
        }
        for (; i < re; ++i) {
            int s = csrc[i];
            unsigned u = ((const unsigned*)(fs + (size_t)s * 128))[lane];
            float x0 = bf_lo(u), x1 = bf_hi(u);
            float t0 = x0 + fd0, t1 = x1 + fd1;
            float p = a06x * t0;
            p = fmaf(a04x, fabsf(t0), p);
            p = fmaf(a06y, t1, p);
            p = fmaf(a04y, fabsf(t1), p);
            p = row16_sum(p);
            float ex = fast_exp2(p);
            denom += ex;
            acc0 = fmaf(ex, x0, acc0);
            acc1 = fmaf(ex, x1, acc1);
        }
        float inv = (re > rs) ? 1.f / denom : 0.f;
        float r0 = fmaxf(acc0 * inv, 0.f);  // fused inter-layer ReLU
        float r1 = fmaxf(acc1 * inv, 0.f);
        ((unsigned*)(out + (size_t)wid * 128))[lane] = (bf_rn(r1) << 16) | bf_rn(r0);
    }
}

// Layer 2: 1 head x 32 feats. 2 edge slots (32 lanes each) x unroll 2.
__global__ __launch_bounds__(256) void conv32(
    const unsigned short* __restrict__ fs, const unsigned short* __restrict__ fd,
    const float* __restrict__ attn, const int* __restrict__ rowp,
    const int* __restrict__ csrc, float* __restrict__ out, int n) {
    const int nwaves = gridDim.x * 4;
    const int wid0 = blockIdx.x * 4 + (threadIdx.x >> 6);
    const int lane = threadIdx.x & 63;
    const int f = lane & 31, slot = lane >> 5;

    float a = attn[f];
    const float a06 = a * 0.6f * LOG2E, a04 = a * 0.4f * LOG2E;

    for (int wid = wid0; wid < n; wid += nwaves) {
        float fdv = bf_one(fd[(size_t)wid * 32 + f]);
        int rs = rowp[wid], re = rowp[wid + 1];
        float acc = 0.f, denom = 0.f;

        int i = rs + slot;
        for (; i + 2 < re; i += 4) {
            int sA = csrc[i], sB = csrc[i + 2];
            float vA = bf_one(fs[(size_t)sA * 32 + f]);
            float vB = bf_one(fs[(size_t)sB * 32 + f]);
            float fv[2] = {vA, vB};
#pragma unroll
            for (int u = 0; u < 2; ++u) {
                float t = fv[u] + fdv;
                float p = a06 * t;
                p = fmaf(a04, fabsf(t), p);
                p = row16_sum(p);
                p += __shfl_xor(p, 16);
                float ex = fast_exp2(p);
                denom += ex;
                acc = fmaf(ex, fv[u], acc);
            }
        }
        for (; i < re; i += 2) {
            int s = csrc[i];
            float fsv = bf_one(fs[(size_t)s * 32 + f]);
            float t = fsv + fdv;
            float p = a06 * t;
            p = fmaf(a04, fabsf(t), p);
            p = row16_sum(p);
            p += __shfl_xor(p, 16);
            float ex = fast_exp2(p);
            denom += ex;
            acc = fmaf(ex, fsv, acc);
        }
        acc   += __shfl_xor(acc, 32);
        denom += __shfl_xor(denom, 32);
        if (slot == 0)
            out[(size_t)wid * 32 + f] = (re > rs) ? acc / denom : 0.f;
    }
}

// ---------------------------------------------------------------------------

extern "C" void kernel_launch(void* const* d_in, const int* in_sizes, int n_in,
                              void* d_out, int out_size, void* d_ws, size_t ws_size,
                              hipStream_t stream) {
    const float* feats = (const float*)d_in[0];
    const int*   src   = (const int*)d_in[1];
    const int*   dst   = (const int*)d_in[2];
    const float* Ws0 = (const float*)d_in[3],  *bs0 = (const float*)d_in[4];
    const float* Wd0 = (const float*)d_in[5],  *bd0 = (const float*)d_in[6];
    const float* a0  = (const float*)d_in[7];
    const float* Ws1 = (const float*)d_in[8],  *bs1 = (const float*)d_in[9];
    const float* Wd1 = (const float*)d_in[10], *bd1 = (const float*)d_in[11];
    const float* a1  = (const float*)d_in[12];
    const float* Ws2 = (const float*)d_in[13], *bs2 = (const float*)d_in[14];
    const float* Wd2 = (const float*)d_in[15], *bd2 = (const float*)d_in[16];
    const float* a2  = (const float*)d_in[17];

    const int N = in_sizes[0] / 128;  // 50000
    const int E = in_sizes[1];        // 800000

    char* ws = (char*)d_ws;
    const size_t featB = (size_t)N * 128 * 2;  // 12.8 MB (bf16)
    unsigned short* xb  = (unsigned short*)(ws);
    unsigned short* hb  = (unsigned short*)(ws + featB);
    unsigned short* fsb = (unsigned short*)(ws + 2 * featB);
    unsigned short* fdb = (unsigned short*)(ws + 3 * featB);
    char* p = ws + 4 * featB;
    unsigned short* wt0 = (unsigned short*)p; p += 256 * 128 * 2;
    unsigned short* wt1 = (unsigned short*)p; p += 256 * 128 * 2;
    unsigned short* wt2 = (unsigned short*)p; p += 64 * 128 * 2;
    int* rowp   = (int*)p;  p += ((size_t)(N + 1) * 4 + 255) / 256 * 256;
    int* cnt    = (int*)p;  p += ((size_t)N * 4 + 255) / 256 * 256;
    int* cur    = (int*)p;  p += ((size_t)N * 4 + 255) / 256 * 256;
    int* bsum   = (int*)p;  p += 1024;
    int* csrc   = (int*)p;

    const int NB = (N + 511) / 512;

    // ---- CSR build ----
    hipMemsetAsync(cnt, 0, (size_t)N * 4, stream);
    count_k<<<(E + 255) / 256, 256, 0, stream>>>(dst, cnt, E);
    block_sums<<<NB, 256, 0, stream>>>(cnt, bsum, N);
    scan_partials<<<1, 64, 0, stream>>>(bsum, rowp, NB, N);
    scan_blocks<<<NB, 256, 0, stream>>>(cnt, bsum, rowp, N);
    hipMemcpyAsync(cur, rowp, (size_t)N * 4, hipMemcpyDeviceToDevice, stream);
    fill_k<<<(E + 255) / 256, 256, 0, stream>>>(src, dst, cur, csrc, E);

    // ---- bf16 conversions ----
    const int n4 = N * 128 / 4;
    convert_feat<<<(n4 + 255) / 256, 256, 0, stream>>>(feats, xb, n4);
    transpose_all<<<(73728 + 255) / 256, 256, 0, stream>>>(Ws0, Wd0, Ws1, Wd1, Ws2, Wd2, wt0, wt1, wt2);

    const int gemmGrid = (N + 127) / 128;
    const int convGrid = 2048;  // 8192 persistent waves = full occupancy at VGPR<=64

    // ---- layer 0 ----
    gemm_dual<256><<<gemmGrid, 256, 0, stream>>>(xb, wt0, bs0, bd0, fsb, fdb, N);
    conv128<<<convGrid, 256, 0, stream>>>(fsb, fdb, a0, rowp, csrc, hb, N);
    // ---- layer 1 ----
    gemm_dual<256><<<gemmGrid, 256, 0, stream>>>(hb, wt1, bs1, bd1, fsb, fdb, N);
    conv128<<<convGrid, 256, 0, stream>>>(fsb, fdb, a1, rowp, csrc, hb, N);
    // ---- layer 2 ----
    gemm_dual<64><<<gemmGrid, 256, 0, stream>>>(hb, wt2, bs2, bd2, fsb, fdb, N);
    conv32<<<convGrid, 256, 0, stream>>>(fsb, fdb, a2, rowp, csrc, (float*)d_out, N);
}

// Round 5
// 365.456 us; speedup vs baseline: 1.6101x; 1.1458x over previous
//
#include <hip/hip_runtime.h>

typedef __attribute__((ext_vector_type(8))) short bf16x8;
typedef __attribute__((ext_vector_type(4))) float f32x4;

#define LOG2E 1.4426950408889634f

__device__ __forceinline__ unsigned bf_rn(float f) {
    unsigned u = __float_as_uint(f);
    u += 0x7fffu + ((u >> 16) & 1u);
    return u >> 16;
}
__device__ __forceinline__ float bf_lo(unsigned u) { return __uint_as_float(u << 16); }
__device__ __forceinline__ float bf_hi(unsigned u) { return __uint_as_float(u & 0xffff0000u); }
__device__ __forceinline__ float bf_one(unsigned short v) { return __uint_as_float((unsigned)v << 16); }

// DPP row-rotate add: cross-lane within 16-lane row on the VALU pipe (no DS).
template <int CTRL>
__device__ __forceinline__ float dpp_radd(float x) {
    int t = __builtin_amdgcn_update_dpp(0, __float_as_int(x), CTRL, 0xF, 0xF, true);
    return x + __int_as_float(t);
}
__device__ __forceinline__ float row16_sum(float p) {
    p = dpp_radd<0x128>(p);  // row_ror:8
    p = dpp_radd<0x124>(p);  // row_ror:4
    p = dpp_radd<0x122>(p);  // row_ror:2
    p = dpp_radd<0x121>(p);  // row_ror:1
    return p;
}
// neighbor swap (lane ^ 1) via quad_perm [1,0,3,2]
__device__ __forceinline__ float dpp_swap1(float x) {
    return __int_as_float(__builtin_amdgcn_update_dpp(0, __float_as_int(x), 0xB1, 0xF, 0xF, true));
}

__device__ __forceinline__ float fast_exp2(float x) {
#if __has_builtin(__builtin_amdgcn_exp2f)
    return __builtin_amdgcn_exp2f(x);
#else
    return __expf(x * 0.6931471805599453f);
#endif
}

// ---------------------------------------------------------------------------
// CSR build (incoming-edge CSR, built once per launch)
// ---------------------------------------------------------------------------

__global__ void count_k(const int* __restrict__ dst, int* __restrict__ cnt, int e) {
    int i = blockIdx.x * blockDim.x + threadIdx.x;
    if (i < e) atomicAdd(&cnt[dst[i]], 1);
}

__global__ void block_sums(const int* __restrict__ cnt, int* __restrict__ bsum, int n) {
    int b = blockIdx.x, t = threadIdx.x;
    int i0 = b * 512 + 2 * t;
    int s = 0;
    if (i0     < n) s += cnt[i0];
    if (i0 + 1 < n) s += cnt[i0 + 1];
    for (int off = 1; off < 64; off <<= 1) s += __shfl_xor(s, off);
    __shared__ int ws4[4];
    if ((t & 63) == 0) ws4[t >> 6] = s;
    __syncthreads();
    if (t == 0) bsum[b] = ws4[0] + ws4[1] + ws4[2] + ws4[3];
}

__global__ void scan_partials(int* __restrict__ bsum, int* __restrict__ rowp, int nb, int n) {
    int l = threadIdx.x;  // 64 threads
    int v0 = (2 * l     < nb) ? bsum[2 * l]     : 0;
    int v1 = (2 * l + 1 < nb) ? bsum[2 * l + 1] : 0;
    int s = v0 + v1;
    for (int off = 1; off < 64; off <<= 1) {
        int t = __shfl_up(s, off);
        if (l >= off) s += t;
    }
    int excl = s - (v0 + v1);
    if (2 * l     < nb) bsum[2 * l]     = excl;
    if (2 * l + 1 < nb) bsum[2 * l + 1] = excl + v0;
    if (l == 63) rowp[n] = s;
}

__global__ void scan_blocks(const int* __restrict__ cnt, const int* __restrict__ bsum,
                            int* __restrict__ rowp, int n) {
    int b = blockIdx.x, t = threadIdx.x;
    int i0 = b * 512 + 2 * t, i1 = i0 + 1;
    int a0 = (i0 < n) ? cnt[i0] : 0;
    int a1 = (i1 < n) ? cnt[i1] : 0;
    int s = a0 + a1;
    int lane = t & 63, w = t >> 6;
    int incl = s;
    for (int off = 1; off < 64; off <<= 1) {
        int tt = __shfl_up(incl, off);
        if (lane >= off) incl += tt;
    }
    __shared__ int wsum[4];
    if (lane == 63) wsum[w] = incl;
    __syncthreads();
    int wpre = 0;
    for (int i = 0; i < w; ++i) wpre += wsum[i];
    int excl = wpre + incl - s + bsum[b];
    if (i0 < n) rowp[i0] = excl;
    if (i1 < n) rowp[i1] = excl + a0;
}

// cur starts as a copy of rowp (d2d); csrc[pos] gets src node
__global__ void fill_k(const int* __restrict__ src, const int* __restrict__ dst,
                       int* __restrict__ cur, int* __restrict__ csrc, int e) {
    int i = blockIdx.x * blockDim.x + threadIdx.x;
    if (i < e) {
        int pos = atomicAdd(&cur[dst[i]], 1);
        csrc[pos] = src[i];
    }
}

// ---------------------------------------------------------------------------
// fp32 -> bf16 conversions (once per launch)
// ---------------------------------------------------------------------------

__global__ void convert_feat(const float* __restrict__ x, unsigned short* __restrict__ o, int n4) {
    int i = blockIdx.x * blockDim.x + threadIdx.x;
    if (i < n4) {
        float4 v = *(const float4*)(x + (size_t)i * 4);
        ushort4 r;
        r.x = (unsigned short)bf_rn(v.x); r.y = (unsigned short)bf_rn(v.y);
        r.z = (unsigned short)bf_rn(v.z); r.w = (unsigned short)bf_rn(v.w);
        *(ushort4*)(o + (size_t)i * 4) = r;
    }
}

// W transpose+convert for all 3 layers in one launch.
__global__ void transpose_all(
    const float* __restrict__ Ws0, const float* __restrict__ Wd0,
    const float* __restrict__ Ws1, const float* __restrict__ Wd1,
    const float* __restrict__ Ws2, const float* __restrict__ Wd2,
    unsigned short* __restrict__ wt0, unsigned short* __restrict__ wt1,
    unsigned short* __restrict__ wt2) {
    int gid = blockIdx.x * blockDim.x + threadIdx.x;
    if (gid < 65536) {  // layers 0,1: 256 c-rows x 128 k each
        int l = gid >> 15, loc = gid & 32767;
        int c = loc >> 7, k = loc & 127;
        const float* W = (c < 128) ? (l ? Ws1 : Ws0) : (l ? Wd1 : Wd0);
        int cc = c & 127;
        float v = W[(size_t)k * 128 + cc];
        (l ? wt1 : wt0)[loc] = (unsigned short)bf_rn(v);
    } else if (gid < 65536 + 8192) {  // layer 2: 64 c-rows x 128 k
        int loc = gid - 65536;
        int c = loc >> 7, k = loc & 127;
        const float* W = (c < 32) ? Ws2 : Wd2;
        int cc = (c < 32) ? c : c - 32;
        float v = W[(size_t)k * 32 + cc];
        wt2[loc] = (unsigned short)bf_rn(v);
    }
}

// ---------------------------------------------------------------------------
// Zero-LDS MFMA dual GEMM: [fs|fd] = x @ [Ws|Wd] + [bs|bd].
// Each wave: 64 rows x 64 cols, A/B fragments loaded directly from global
// (L2/L3-resident). NC = COLS2/64 col-slices; wave gwid -> (chunk, cslice).
// Epilogue: DPP neighbor-swap packs bf16 col-pairs -> coalesced dword stores.
// D layout: row = quad*4 + j, col = m  [m89/m91 verified].
// Rows >= n in x may be garbage: they only affect their own (unstored) rows.
// ---------------------------------------------------------------------------

template <int COLS2>
__global__ __launch_bounds__(256) void gemm_dual2(
    const unsigned short* __restrict__ xb, const unsigned short* __restrict__ wt,
    const float* __restrict__ bs, const float* __restrict__ bd,
    unsigned short* __restrict__ fs, unsigned short* __restrict__ fd,
    int n, int nch) {
    constexpr int C  = COLS2 / 2;
    constexpr int NC = COLS2 / 64;   // col-slices (4 or 1)

    const int lane = threadIdx.x & 63;
    const int m = lane & 15, quad = lane >> 4;
    const int gwid = blockIdx.x * 4 + (threadIdx.x >> 6);
    const int nwaves = gridDim.x * 4;
    const int cs = gwid % NC;
    const int cstride = nwaves / NC;

    // per-lane bias for this wave's 4 col-tiles (col = cs*64 + ct*16 + m)
    float biasv[4];
#pragma unroll
    for (int ct = 0; ct < 4; ++ct) {
        int col = cs * 64 + ct * 16 + m;
        biasv[ct] = (col < C) ? bs[col] : bd[col - C];
    }

    for (int chunk = gwid / NC; chunk < nch; chunk += cstride) {
        const size_t r0 = (size_t)chunk * 64;

        f32x4 acc[4][4];
#pragma unroll
        for (int rt = 0; rt < 4; ++rt)
#pragma unroll
            for (int ct = 0; ct < 4; ++ct) acc[rt][ct] = (f32x4){0.f, 0.f, 0.f, 0.f};

#pragma unroll
        for (int ks = 0; ks < 4; ++ks) {
            const int ko = ks * 32 + quad * 8;
            bf16x8 a[4], b[4];
#pragma unroll
            for (int rt = 0; rt < 4; ++rt)
                a[rt] = *(const bf16x8*)(xb + (r0 + rt * 16 + m) * 128 + ko);
#pragma unroll
            for (int ct = 0; ct < 4; ++ct)
                b[ct] = *(const bf16x8*)(wt + (size_t)(cs * 64 + ct * 16 + m) * 128 + ko);
#pragma unroll
            for (int rt = 0; rt < 4; ++rt)
#pragma unroll
                for (int ct = 0; ct < 4; ++ct)
                    acc[rt][ct] = __builtin_amdgcn_mfma_f32_16x16x32_bf16(a[rt], b[ct], acc[rt][ct], 0, 0, 0);
        }

        // Epilogue: pack adjacent-col bf16 pairs via DPP neighbor swap.
        const int odd = m & 1;
#pragma unroll
        for (int ct = 0; ct < 4; ++ct) {
            int colE = cs * 64 + ct * 16 + (m & ~1);
            unsigned short* ptr = (colE < C) ? fs : fd;
            int cc = (colE < C) ? colE : colE - C;
#pragma unroll
            for (int rt = 0; rt < 4; ++rt) {
                float v0 = acc[rt][ct][0] + biasv[ct];
                float v1 = acc[rt][ct][1] + biasv[ct];
                float v2 = acc[rt][ct][2] + biasv[ct];
                float v3 = acc[rt][ct][3] + biasv[ct];
                float s0 = dpp_swap1(v0), s1 = dpp_swap1(v1);
                float s2 = dpp_swap1(v2), s3 = dpp_swap1(v3);
                // even lanes: rows quad*4+{0,1}; odd lanes: rows quad*4+{2,3}
                float aLo = odd ? s2 : v0, aHi = odd ? v2 : s0;
                float bLo = odd ? s3 : v1, bHi = odd ? v3 : s1;
                int rowA = (int)r0 + rt * 16 + quad * 4 + (odd ? 2 : 0);
                unsigned pa = (bf_rn(aHi) << 16) | bf_rn(aLo);
                unsigned pb = (bf_rn(bHi) << 16) | bf_rn(bLo);
                if (rowA < n)     *(unsigned*)(ptr + (size_t)rowA * C + cc)       = pa;
                if (rowA + 1 < n) *(unsigned*)(ptr + ((size_t)rowA + 1) * C + cc) = pb;
            }
        }
    }
}

// ---------------------------------------------------------------------------
// GATv2 aggregation: dst-centric, persistent waves, DPP row reduction,
// leaky = 0.6x+0.4|x| with pre-scaled attn (log2e folded), exp2.
// ---------------------------------------------------------------------------

__global__ __launch_bounds__(256) void conv128(
    const unsigned short* __restrict__ fs, const unsigned short* __restrict__ fd,
    const float* __restrict__ attn, const int* __restrict__ rowp,
    const int* __restrict__ csrc, unsigned short* __restrict__ out, int n) {
    const int nwaves = gridDim.x * 4;
    const int wid0 = blockIdx.x * 4 + (threadIdx.x >> 6);
    const int lane = threadIdx.x & 63;

    float2 av = *(const float2*)(attn + lane * 2);
    const float a06x = av.x * 0.6f * LOG2E, a04x = av.x * 0.4f * LOG2E;
    const float a06y = av.y * 0.6f * LOG2E, a04y = av.y * 0.4f * LOG2E;

    for (int wid = wid0; wid < n; wid += nwaves) {
        unsigned ud = ((const unsigned*)(fd + (size_t)wid * 128))[lane];
        float fd0 = bf_lo(ud), fd1 = bf_hi(ud);
        int rs = rowp[wid], re = rowp[wid + 1];
        float acc0 = 0.f, acc1 = 0.f, denom = 0.f;

        int i = rs;
        for (; i + 4 <= re; i += 4) {
            int s0 = csrc[i], s1 = csrc[i + 1], s2 = csrc[i + 2], s3 = csrc[i + 3];
            unsigned u0 = ((const unsigned*)(fs + (size_t)s0 * 128))[lane];
            unsigned u1 = ((const unsigned*)(fs + (size_t)s1 * 128))[lane];
            unsigned u2 = ((const unsigned*)(fs + (size_t)s2 * 128))[lane];
            unsigned u3 = ((const unsigned*)(fs + (size_t)s3 * 128))[lane];
            unsigned uu[4] = {u0, u1, u2, u3};
#pragma unroll
            for (int u = 0; u < 4; ++u) {
                float x0 = bf_lo(uu[u]), x1 = bf_hi(uu[u]);
                float t0 = x0 + fd0, t1 = x1 + fd1;
                float p = a06x * t0;
                p = fmaf(a04x, fabsf(t0), p);
                p = fmaf(a06y, t1, p);
                p = fmaf(a04y, fabsf(t1), p);
                p = row16_sum(p);
                float ex = fast_exp2(p);
                denom += ex;
                acc0 = fmaf(ex, x0, acc0);
                acc1 = fmaf(ex, x1, acc1);
            }
        }
        for (; i < re; ++i) {
            int s = csrc[i];
            unsigned u = ((const unsigned*)(fs + (size_t)s * 128))[lane];
            float x0 = bf_lo(u), x1 = bf_hi(u);
            float t0 = x0 + fd0, t1 = x1 + fd1;
            float p = a06x * t0;
            p = fmaf(a04x, fabsf(t0), p);
            p = fmaf(a06y, t1, p);
            p = fmaf(a04y, fabsf(t1), p);
            p = row16_sum(p);
            float ex = fast_exp2(p);
            denom += ex;
            acc0 = fmaf(ex, x0, acc0);
            acc1 = fmaf(ex, x1, acc1);
        }
        float inv = (re > rs) ? 1.f / denom : 0.f;
        float r0 = fmaxf(acc0 * inv, 0.f);  // fused inter-layer ReLU
        float r1 = fmaxf(acc1 * inv, 0.f);
        ((unsigned*)(out + (size_t)wid * 128))[lane] = (bf_rn(r1) << 16) | bf_rn(r0);
    }
}

// Layer 2: 1 head x 32 feats. 2 edge slots (32 lanes each) x unroll 2.
__global__ __launch_bounds__(256) void conv32(
    const unsigned short* __restrict__ fs, const unsigned short* __restrict__ fd,
    const float* __restrict__ attn, const int* __restrict__ rowp,
    const int* __restrict__ csrc, float* __restrict__ out, int n) {
    const int nwaves = gridDim.x * 4;
    const int wid0 = blockIdx.x * 4 + (threadIdx.x >> 6);
    const int lane = threadIdx.x & 63;
    const int f = lane & 31, slot = lane >> 5;

    float a = attn[f];
    const float a06 = a * 0.6f * LOG2E, a04 = a * 0.4f * LOG2E;

    for (int wid = wid0; wid < n; wid += nwaves) {
        float fdv = bf_one(fd[(size_t)wid * 32 + f]);
        int rs = rowp[wid], re = rowp[wid + 1];
        float acc = 0.f, denom = 0.f;

        int i = rs + slot;
        for (; i + 2 < re; i += 4) {
            int sA = csrc[i], sB = csrc[i + 2];
            float vA = bf_one(fs[(size_t)sA * 32 + f]);
            float vB = bf_one(fs[(size_t)sB * 32 + f]);
            float fv[2] = {vA, vB};
#pragma unroll
            for (int u = 0; u < 2; ++u) {
                float t = fv[u] + fdv;
                float p = a06 * t;
                p = fmaf(a04, fabsf(t), p);
                p = row16_sum(p);
                p += __shfl_xor(p, 16);
                float ex = fast_exp2(p);
                denom += ex;
                acc = fmaf(ex, fv[u], acc);
            }
        }
        for (; i < re; i += 2) {
            int s = csrc[i];
            float fsv = bf_one(fs[(size_t)s * 32 + f]);
            float t = fsv + fdv;
            float p = a06 * t;
            p = fmaf(a04, fabsf(t), p);
            p = row16_sum(p);
            p += __shfl_xor(p, 16);
            float ex = fast_exp2(p);
            denom += ex;
            acc = fmaf(ex, fsv, acc);
        }
        acc   += __shfl_xor(acc, 32);
        denom += __shfl_xor(denom, 32);
        if (slot == 0)
            out[(size_t)wid * 32 + f] = (re > rs) ? acc / denom : 0.f;
    }
}

// ---------------------------------------------------------------------------

extern "C" void kernel_launch(void* const* d_in, const int* in_sizes, int n_in,
                              void* d_out, int out_size, void* d_ws, size_t ws_size,
                              hipStream_t stream) {
    const float* feats = (const float*)d_in[0];
    const int*   src   = (const int*)d_in[1];
    const int*   dst   = (const int*)d_in[2];
    const float* Ws0 = (const float*)d_in[3],  *bs0 = (const float*)d_in[4];
    const float* Wd0 = (const float*)d_in[5],  *bd0 = (const float*)d_in[6];
    const float* a0  = (const float*)d_in[7];
    const float* Ws1 = (const float*)d_in[8],  *bs1 = (const float*)d_in[9];
    const float* Wd1 = (const float*)d_in[10], *bd1 = (const float*)d_in[11];
    const float* a1  = (const float*)d_in[12];
    const float* Ws2 = (const float*)d_in[13], *bs2 = (const float*)d_in[14];
    const float* Wd2 = (const float*)d_in[15], *bd2 = (const float*)d_in[16];
    const float* a2  = (const float*)d_in[17];

    const int N = in_sizes[0] / 128;  // 50000
    const int E = in_sizes[1];        // 800000
    const int nch = (N + 63) / 64;    // 782 row-chunks
    const int NPAD = nch * 64;        // padded row count (gemm reads to here)

    char* ws = (char*)d_ws;
    const size_t featB = (size_t)NPAD * 128 * 2;  // padded bf16 feat buffer
    unsigned short* xb  = (unsigned short*)(ws);
    unsigned short* hb  = (unsigned short*)(ws + featB);
    unsigned short* fsb = (unsigned short*)(ws + 2 * featB);
    unsigned short* fdb = (unsigned short*)(ws + 3 * featB);
    char* p = ws + 4 * featB;
    unsigned short* wt0 = (unsigned short*)p; p += 256 * 128 * 2;
    unsigned short* wt1 = (unsigned short*)p; p += 256 * 128 * 2;
    unsigned short* wt2 = (unsigned short*)p; p += 64 * 128 * 2;
    int* rowp   = (int*)p;  p += ((size_t)(N + 1) * 4 + 255) / 256 * 256;
    int* cnt    = (int*)p;  p += ((size_t)N * 4 + 255) / 256 * 256;
    int* cur    = (int*)p;  p += ((size_t)N * 4 + 255) / 256 * 256;
    int* bsum   = (int*)p;  p += 1024;
    int* csrc   = (int*)p;

    const int NB = (N + 511) / 512;

    // ---- CSR build ----
    hipMemsetAsync(cnt, 0, (size_t)N * 4, stream);
    count_k<<<(E + 255) / 256, 256, 0, stream>>>(dst, cnt, E);
    block_sums<<<NB, 256, 0, stream>>>(cnt, bsum, N);
    scan_partials<<<1, 64, 0, stream>>>(bsum, rowp, NB, N);
    scan_blocks<<<NB, 256, 0, stream>>>(cnt, bsum, rowp, N);
    hipMemcpyAsync(cur, rowp, (size_t)N * 4, hipMemcpyDeviceToDevice, stream);
    fill_k<<<(E + 255) / 256, 256, 0, stream>>>(src, dst, cur, csrc, E);

    // ---- bf16 conversions ----
    const int n4 = N * 128 / 4;
    convert_feat<<<(n4 + 255) / 256, 256, 0, stream>>>(feats, xb, n4);
    transpose_all<<<(73728 + 255) / 256, 256, 0, stream>>>(Ws0, Wd0, Ws1, Wd1, Ws2, Wd2, wt0, wt1, wt2);

    // gemm256: nch chunks x 4 col-slices, 1 wave each -> grid = nch blocks
    // gemm64:  nch chunks x 1 col-slice -> grid = ceil(nch/4) blocks
    const int g256 = nch;
    const int g64  = (nch + 3) / 4;
    const int convGrid = 2048;  // 8192 persistent waves

    // ---- layer 0 ----
    gemm_dual2<256><<<g256, 256, 0, stream>>>(xb, wt0, bs0, bd0, fsb, fdb, N, nch);
    conv128<<<convGrid, 256, 0, stream>>>(fsb, fdb, a0, rowp, csrc, hb, N);
    // ---- layer 1 ----
    gemm_dual2<256><<<g256, 256, 0, stream>>>(hb, wt1, bs1, bd1, fsb, fdb, N, nch);
    conv128<<<convGrid, 256, 0, stream>>>(fsb, fdb, a1, rowp, csrc, hb, N);
    // ---- layer 2 ----
    gemm_dual2<64><<<g64, 256, 0, stream>>>(hb, wt2, bs2, bd2, fsb, fdb, N, nch);
    conv32<<<convGrid, 256, 0, stream>>>(fsb, fdb, a2, rowp, csrc, (float*)d_out, N);
}

// Round 6
// 309.765 us; speedup vs baseline: 1.8995x; 1.1798x over previous
//
#include <hip/hip_runtime.h>

typedef __attribute__((ext_vector_type(8))) short bf16x8;
typedef __attribute__((ext_vector_type(4))) float f32x4;

#define LOG2E 1.4426950408889634f

// CSR binning parameters: bins of 256 dst nodes
#define BINSH 8
#define NBIN 196        // ceil(50000/256)
#define CHUNK 4096      // edges per bin_scatter block
#define K4CAP 6144      // staged edges per bin in csr_build (avg 4096)

__device__ __forceinline__ unsigned bf_rn(float f) {
    unsigned u = __float_as_uint(f);
    u += 0x7fffu + ((u >> 16) & 1u);
    return u >> 16;
}
__device__ __forceinline__ float bf_lo(unsigned u) { return __uint_as_float(u << 16); }
__device__ __forceinline__ float bf_hi(unsigned u) { return __uint_as_float(u & 0xffff0000u); }
__device__ __forceinline__ float bf_one(unsigned short v) { return __uint_as_float((unsigned)v << 16); }

// DPP row-rotate add: cross-lane within 16-lane row on the VALU pipe (no DS).
template <int CTRL>
__device__ __forceinline__ float dpp_radd(float x) {
    int t = __builtin_amdgcn_update_dpp(0, __float_as_int(x), CTRL, 0xF, 0xF, true);
    return x + __int_as_float(t);
}
__device__ __forceinline__ float row16_sum(float p) {
    p = dpp_radd<0x128>(p);  // row_ror:8
    p = dpp_radd<0x124>(p);  // row_ror:4
    p = dpp_radd<0x122>(p);  // row_ror:2
    p = dpp_radd<0x121>(p);  // row_ror:1
    return p;
}
// neighbor swap (lane ^ 1) via quad_perm [1,0,3,2]
__device__ __forceinline__ float dpp_swap1(float x) {
    return __int_as_float(__builtin_amdgcn_update_dpp(0, __float_as_int(x), 0xB1, 0xF, 0xF, true));
}

__device__ __forceinline__ float fast_exp2(float x) {
#if __has_builtin(__builtin_amdgcn_exp2f)
    return __builtin_amdgcn_exp2f(x);
#else
    return __expf(x * 0.6931471805599453f);
#endif
}

// ---------------------------------------------------------------------------
// Binned CSR build (2-pass radix on dst; ~40k atomics instead of 1.6M)
// ---------------------------------------------------------------------------

// K1: per-block LDS histogram over bins, one global atomic per (block,bin)
__global__ __launch_bounds__(256) void bin_count(const int* __restrict__ dst,
                                                 int* __restrict__ binCnt, int e) {
    __shared__ int hist[NBIN];
    for (int t = threadIdx.x; t < NBIN; t += 256) hist[t] = 0;
    __syncthreads();
    int base = blockIdx.x * CHUNK;
    int cnt = min(CHUNK, e - base);
    for (int j = threadIdx.x; j < cnt; j += 256)
        atomicAdd(&hist[dst[base + j] >> BINSH], 1);
    __syncthreads();
    for (int t = threadIdx.x; t < NBIN; t += 256)
        if (hist[t]) atomicAdd(&binCnt[t], hist[t]);
}

// K2: one block, 256 threads: exclusive scan of binCnt -> binBase, binCur
__global__ void bin_scan(const int* __restrict__ binCnt, int* __restrict__ binBase,
                         int* __restrict__ binCur, int* __restrict__ rowp, int n, int e) {
    int t = threadIdx.x;
    int v = (t < NBIN) ? binCnt[t] : 0;
    int lane = t & 63, w = t >> 6;
    int incl = v;
    for (int off = 1; off < 64; off <<= 1) {
        int tt = __shfl_up(incl, off);
        if (lane >= off) incl += tt;
    }
    __shared__ int wsum[4];
    if (lane == 63) wsum[w] = incl;
    __syncthreads();
    int wpre = 0;
    for (int i = 0; i < w; ++i) wpre += wsum[i];
    int excl = wpre + incl - v;
    if (t < NBIN) { binBase[t] = excl; binCur[t] = excl; }
    if (t == 0) { binBase[NBIN] = e; rowp[n] = e; }
}

// K3: LDS counting-sort of a 4096-edge chunk by bin, then group-coalesced
// append to each bin's region. pack = bin(8b) | dstLow(8b) | src(16b).
__global__ __launch_bounds__(256) void bin_scatter(
    const int* __restrict__ src, const int* __restrict__ dst,
    int* __restrict__ binCur, unsigned* __restrict__ ebin, int e) {
    __shared__ int hist[NBIN];
    __shared__ int seg[NBIN];
    __shared__ int gbase[NBIN];
    __shared__ unsigned pack[CHUNK];
    for (int t = threadIdx.x; t < NBIN; t += 256) hist[t] = 0;
    __syncthreads();
    int base = blockIdx.x * CHUNK;
    int cnt = min(CHUNK, e - base);

    int myb[CHUNK / 256], myr[CHUNK / 256];
    unsigned myw[CHUNK / 256];
    int nmine = 0;
    for (int j = threadIdx.x; j < cnt; j += 256) {
        int d = dst[base + j], s = src[base + j];
        int b = d >> BINSH, dl = d & ((1 << BINSH) - 1);
        int r = atomicAdd(&hist[b], 1);
        myb[nmine] = b; myr[nmine] = r;
        myw[nmine] = ((unsigned)b << 24) | ((unsigned)dl << 16) | (unsigned)s;
        ++nmine;
    }
    __syncthreads();
    if (threadIdx.x == 0) {
        int acc = 0;
        for (int b2 = 0; b2 < NBIN; ++b2) { seg[b2] = acc; acc += hist[b2]; }
    }
    __syncthreads();
    for (int k = 0; k < nmine; ++k)
        pack[seg[myb[k]] + myr[k]] = myw[k];
    __syncthreads();
    if (threadIdx.x < NBIN && hist[threadIdx.x])
        gbase[threadIdx.x] = atomicAdd(&binCur[threadIdx.x], hist[threadIdx.x]);
    __syncthreads();
    for (int j = threadIdx.x; j < cnt; j += 256) {
        unsigned wv = pack[j];
        int b = wv >> 24;
        ebin[gbase[b] + (j - seg[b])] = wv;
    }
}

// K4: one block per bin. LDS hist+scan over the bin's 256 nodes -> rowp
// segment (coalesced) + csrc scatter confined to one contiguous window
// (single block => single XCD L2 => full-line writebacks).
__global__ __launch_bounds__(256) void csr_build(
    const unsigned* __restrict__ ebin, const int* __restrict__ binBase,
    int* __restrict__ rowp, int* __restrict__ csrc, int n) {
    __shared__ int hist[256];
    __shared__ int seg[256];
    __shared__ unsigned stage[K4CAP];
    int b = blockIdx.x;
    int e0 = binBase[b], e1 = binBase[b + 1];
    int n0 = b << BINSH;
    int nn = min(256, n - n0);
    for (int t = threadIdx.x; t < 256; t += 256) hist[t] = 0;
    __syncthreads();
    for (int i = e0 + threadIdx.x; i < e1; i += 256) {
        unsigned wv = ebin[i];
        atomicAdd(&hist[(wv >> 16) & 255], 1);
        int off = i - e0;
        if (off < K4CAP) stage[off] = wv;
    }
    __syncthreads();
    // exclusive scan of hist[256] using wave 0 (64 lanes x 4)
    if (threadIdx.x < 64) {
        int l = threadIdx.x;
        int s = 0, loc[4];
#pragma unroll
        for (int k = 0; k < 4; ++k) { loc[k] = s; s += hist[l * 4 + k]; }
        int incl = s;
        for (int off = 1; off < 64; off <<= 1) {
            int tt = __shfl_up(incl, off);
            if (l >= off) incl += tt;
        }
        int excl = incl - s;
#pragma unroll
        for (int k = 0; k < 4; ++k) seg[l * 4 + k] = excl + loc[k];
    }
    __syncthreads();
    for (int t = threadIdx.x; t < nn; t += 256) rowp[n0 + t] = e0 + seg[t];
    for (int t = threadIdx.x; t < 256; t += 256) hist[t] = seg[t];  // cursors
    __syncthreads();
    for (int i = e0 + threadIdx.x; i < e1; i += 256) {
        int off = i - e0;
        unsigned wv = (off < K4CAP) ? stage[off] : ebin[i];
        int dl = (wv >> 16) & 255;
        int pos = e0 + atomicAdd(&hist[dl], 1);
        csrc[pos] = (int)(wv & 0xFFFFu);
    }
}

// ---------------------------------------------------------------------------
// fp32 -> bf16 conversions (once per launch)
// ---------------------------------------------------------------------------

__global__ void convert_feat(const float* __restrict__ x, unsigned short* __restrict__ o, int n4) {
    int i = blockIdx.x * blockDim.x + threadIdx.x;
    if (i < n4) {
        float4 v = *(const float4*)(x + (size_t)i * 4);
        ushort4 r;
        r.x = (unsigned short)bf_rn(v.x); r.y = (unsigned short)bf_rn(v.y);
        r.z = (unsigned short)bf_rn(v.z); r.w = (unsigned short)bf_rn(v.w);
        *(ushort4*)(o + (size_t)i * 4) = r;
    }
}

// W transpose+convert for all 3 layers in one launch.
__global__ void transpose_all(
    const float* __restrict__ Ws0, const float* __restrict__ Wd0,
    const float* __restrict__ Ws1, const float* __restrict__ Wd1,
    const float* __restrict__ Ws2, const float* __restrict__ Wd2,
    unsigned short* __restrict__ wt0, unsigned short* __restrict__ wt1,
    unsigned short* __restrict__ wt2) {
    int gid = blockIdx.x * blockDim.x + threadIdx.x;
    if (gid < 65536) {  // layers 0,1: 256 c-rows x 128 k each
        int l = gid >> 15, loc = gid & 32767;
        int c = loc >> 7, k = loc & 127;
        const float* W = (c < 128) ? (l ? Ws1 : Ws0) : (l ? Wd1 : Wd0);
        int cc = c & 127;
        float v = W[(size_t)k * 128 + cc];
        (l ? wt1 : wt0)[loc] = (unsigned short)bf_rn(v);
    } else if (gid < 65536 + 8192) {  // layer 2: 64 c-rows x 128 k
        int loc = gid - 65536;
        int c = loc >> 7, k = loc & 127;
        const float* W = (c < 32) ? Ws2 : Wd2;
        int cc = (c < 32) ? c : c - 32;
        float v = W[(size_t)k * 32 + cc];
        wt2[loc] = (unsigned short)bf_rn(v);
    }
}

// ---------------------------------------------------------------------------
// Zero-LDS MFMA dual GEMM: [fs|fd] = x @ [Ws|Wd] + [bs|bd].
// Each wave: 64 rows x 64 cols, fragments loaded directly from global.
// ---------------------------------------------------------------------------

template <int COLS2>
__global__ __launch_bounds__(256) void gemm_dual2(
    const unsigned short* __restrict__ xb, const unsigned short* __restrict__ wt,
    const float* __restrict__ bs, const float* __restrict__ bd,
    unsigned short* __restrict__ fs, unsigned short* __restrict__ fd,
    int n, int nch) {
    constexpr int C  = COLS2 / 2;
    constexpr int NC = COLS2 / 64;   // col-slices (4 or 1)

    const int lane = threadIdx.x & 63;
    const int m = lane & 15, quad = lane >> 4;
    const int gwid = blockIdx.x * 4 + (threadIdx.x >> 6);
    const int nwaves = gridDim.x * 4;
    const int cs = gwid % NC;
    const int cstride = nwaves / NC;

    float biasv[4];
#pragma unroll
    for (int ct = 0; ct < 4; ++ct) {
        int col = cs * 64 + ct * 16 + m;
        biasv[ct] = (col < C) ? bs[col] : bd[col - C];
    }

    for (int chunk = gwid / NC; chunk < nch; chunk += cstride) {
        const size_t r0 = (size_t)chunk * 64;

        f32x4 acc[4][4];
#pragma unroll
        for (int rt = 0; rt < 4; ++rt)
#pragma unroll
            for (int ct = 0; ct < 4; ++ct) acc[rt][ct] = (f32x4){0.f, 0.f, 0.f, 0.f};

#pragma unroll
        for (int ks = 0; ks < 4; ++ks) {
            const int ko = ks * 32 + quad * 8;
            bf16x8 a[4], b[4];
#pragma unroll
            for (int rt = 0; rt < 4; ++rt)
                a[rt] = *(const bf16x8*)(xb + (r0 + rt * 16 + m) * 128 + ko);
#pragma unroll
            for (int ct = 0; ct < 4; ++ct)
                b[ct] = *(const bf16x8*)(wt + (size_t)(cs * 64 + ct * 16 + m) * 128 + ko);
#pragma unroll
            for (int rt = 0; rt < 4; ++rt)
#pragma unroll
                for (int ct = 0; ct < 4; ++ct)
                    acc[rt][ct] = __builtin_amdgcn_mfma_f32_16x16x32_bf16(a[rt], b[ct], acc[rt][ct], 0, 0, 0);
        }

        const int odd = m & 1;
#pragma unroll
        for (int ct = 0; ct < 4; ++ct) {
            int colE = cs * 64 + ct * 16 + (m & ~1);
            unsigned short* ptr = (colE < C) ? fs : fd;
            int cc = (colE < C) ? colE : colE - C;
#pragma unroll
            for (int rt = 0; rt < 4; ++rt) {
                float v0 = acc[rt][ct][0] + biasv[ct];
                float v1 = acc[rt][ct][1] + biasv[ct];
                float v2 = acc[rt][ct][2] + biasv[ct];
                float v3 = acc[rt][ct][3] + biasv[ct];
                float s0 = dpp_swap1(v0), s1 = dpp_swap1(v1);
                float s2 = dpp_swap1(v2), s3 = dpp_swap1(v3);
                float aLo = odd ? s2 : v0, aHi = odd ? v2 : s0;
                float bLo = odd ? s3 : v1, bHi = odd ? v3 : s1;
                int rowA = (int)r0 + rt * 16 + quad * 4 + (odd ? 2 : 0);
                unsigned pa = (bf_rn(aHi) << 16) | bf_rn(aLo);
                unsigned pb = (bf_rn(bHi) << 16) | bf_rn(bLo);
                if (rowA < n)     *(unsigned*)(ptr + (size_t)rowA * C + cc)       = pa;
                if (rowA + 1 < n) *(unsigned*)(ptr + ((size_t)rowA + 1) * C + cc) = pb;
            }
        }
    }
}

// ---------------------------------------------------------------------------
// GATv2 aggregation: dst-centric, persistent waves, DPP row reduction,
// leaky = 0.6x+0.4|x| with pre-scaled attn (log2e folded), exp2.
// ---------------------------------------------------------------------------

__global__ __launch_bounds__(256) void conv128(
    const unsigned short* __restrict__ fs, const unsigned short* __restrict__ fd,
    const float* __restrict__ attn, const int* __restrict__ rowp,
    const int* __restrict__ csrc, unsigned short* __restrict__ out, int n) {
    const int nwaves = gridDim.x * 4;
    const int wid0 = blockIdx.x * 4 + (threadIdx.x >> 6);
    const int lane = threadIdx.x & 63;

    float2 av = *(const float2*)(attn + lane * 2);
    const float a06x = av.x * 0.6f * LOG2E, a04x = av.x * 0.4f * LOG2E;
    const float a06y = av.y * 0.6f * LOG2E, a04y = av.y * 0.4f * LOG2E;

    for (int wid = wid0; wid < n; wid += nwaves) {
        unsigned ud = ((const unsigned*)(fd + (size_t)wid * 128))[lane];
        float fd0 = bf_lo(ud), fd1 = bf_hi(ud);
        int rs = rowp[wid], re = rowp[wid + 1];
        float acc0 = 0.f, acc1 = 0.f, denom = 0.f;

        int i = rs;
        for (; i + 4 <= re; i += 4) {
            int s0 = csrc[i], s1 = csrc[i + 1], s2 = csrc[i + 2], s3 = csrc[i + 3];
            unsigned u0 = ((const unsigned*)(fs + (size_t)s0 * 128))[lane];
            unsigned u1 = ((const unsigned*)(fs + (size_t)s1 * 128))[lane];
            unsigned u2 = ((const unsigned*)(fs + (size_t)s2 * 128))[lane];
            unsigned u3 = ((const unsigned*)(fs + (size_t)s3 * 128))[lane];
            unsigned uu[4] = {u0, u1, u2, u3};
#pragma unroll
            for (int u = 0; u < 4; ++u) {
                float x0 = bf_lo(uu[u]), x1 = bf_hi(uu[u]);
                float t0 = x0 + fd0, t1 = x1 + fd1;
                float p = a06x * t0;
                p = fmaf(a04x, fabsf(t0), p);
                p = fmaf(a06y, t1, p);
                p = fmaf(a04y, fabsf(t1), p);
                p = row16_sum(p);
                float ex = fast_exp2(p);
                denom += ex;
                acc0 = fmaf(ex, x0, acc0);
                acc1 = fmaf(ex, x1, acc1);
            }
        }
        for (; i < re; ++i) {
            int s = csrc[i];
            unsigned u = ((const unsigned*)(fs + (size_t)s * 128))[lane];
            float x0 = bf_lo(u), x1 = bf_hi(u);
            float t0 = x0 + fd0, t1 = x1 + fd1;
            float p = a06x * t0;
            p = fmaf(a04x, fabsf(t0), p);
            p = fmaf(a06y, t1, p);
            p = fmaf(a04y, fabsf(t1), p);
            p = row16_sum(p);
            float ex = fast_exp2(p);
            denom += ex;
            acc0 = fmaf(ex, x0, acc0);
            acc1 = fmaf(ex, x1, acc1);
        }
        float inv = (re > rs) ? 1.f / denom : 0.f;
        float r0 = fmaxf(acc0 * inv, 0.f);  // fused inter-layer ReLU
        float r1 = fmaxf(acc1 * inv, 0.f);
        ((unsigned*)(out + (size_t)wid * 128))[lane] = (bf_rn(r1) << 16) | bf_rn(r0);
    }
}

// Layer 2: 1 head x 32 feats. 2 edge slots (32 lanes each) x unroll 2.
__global__ __launch_bounds__(256) void conv32(
    const unsigned short* __restrict__ fs, const unsigned short* __restrict__ fd,
    const float* __restrict__ attn, const int* __restrict__ rowp,
    const int* __restrict__ csrc, float* __restrict__ out, int n) {
    const int nwaves = gridDim.x * 4;
    const int wid0 = blockIdx.x * 4 + (threadIdx.x >> 6);
    const int lane = threadIdx.x & 63;
    const int f = lane & 31, slot = lane >> 5;

    float a = attn[f];
    const float a06 = a * 0.6f * LOG2E, a04 = a * 0.4f * LOG2E;

    for (int wid = wid0; wid < n; wid += nwaves) {
        float fdv = bf_one(fd[(size_t)wid * 32 + f]);
        int rs = rowp[wid], re = rowp[wid + 1];
        float acc = 0.f, denom = 0.f;

        int i = rs + slot;
        for (; i + 2 < re; i += 4) {
            int sA = csrc[i], sB = csrc[i + 2];
            float vA = bf_one(fs[(size_t)sA * 32 + f]);
            float vB = bf_one(fs[(size_t)sB * 32 + f]);
            float fv[2] = {vA, vB};
#pragma unroll
            for (int u = 0; u < 2; ++u) {
                float t = fv[u] + fdv;
                float p = a06 * t;
                p = fmaf(a04, fabsf(t), p);
                p = row16_sum(p);
                p += __shfl_xor(p, 16);
                float ex = fast_exp2(p);
                denom += ex;
                acc = fmaf(ex, fv[u], acc);
            }
        }
        for (; i < re; i += 2) {
            int s = csrc[i];
            float fsv = bf_one(fs[(size_t)s * 32 + f]);
            float t = fsv + fdv;
            float p = a06 * t;
            p = fmaf(a04, fabsf(t), p);
            p = row16_sum(p);
            p += __shfl_xor(p, 16);
            float ex = fast_exp2(p);
            denom += ex;
            acc = fmaf(ex, fsv, acc);
        }
        acc   += __shfl_xor(acc, 32);
        denom += __shfl_xor(denom, 32);
        if (slot == 0)
            out[(size_t)wid * 32 + f] = (re > rs) ? acc / denom : 0.f;
    }
}

// ---------------------------------------------------------------------------

extern "C" void kernel_launch(void* const* d_in, const int* in_sizes, int n_in,
                              void* d_out, int out_size, void* d_ws, size_t ws_size,
                              hipStream_t stream) {
    const float* feats = (const float*)d_in[0];
    const int*   src   = (const int*)d_in[1];
    const int*   dst   = (const int*)d_in[2];
    const float* Ws0 = (const float*)d_in[3],  *bs0 = (const float*)d_in[4];
    const float* Wd0 = (const float*)d_in[5],  *bd0 = (const float*)d_in[6];
    const float* a0  = (const float*)d_in[7];
    const float* Ws1 = (const float*)d_in[8],  *bs1 = (const float*)d_in[9];
    const float* Wd1 = (const float*)d_in[10], *bd1 = (const float*)d_in[11];
    const float* a1  = (const float*)d_in[12];
    const float* Ws2 = (const float*)d_in[13], *bs2 = (const float*)d_in[14];
    const float* Wd2 = (const float*)d_in[15], *bd2 = (const float*)d_in[16];
    const float* a2  = (const float*)d_in[17];

    const int N = in_sizes[0] / 128;  // 50000
    const int E = in_sizes[1];        // 800000
    const int nch = (N + 63) / 64;    // row-chunks for gemm
    const int NPAD = nch * 64;

    char* ws = (char*)d_ws;
    const size_t featB = (size_t)NPAD * 128 * 2;  // padded bf16 feat buffer
    unsigned short* xb  = (unsigned short*)(ws);
    unsigned short* hb  = (unsigned short*)(ws + featB);
    unsigned short* fsb = (unsigned short*)(ws + 2 * featB);
    unsigned short* fdb = (unsigned short*)(ws + 3 * featB);
    char* p = ws + 4 * featB;
    unsigned short* wt0 = (unsigned short*)p; p += 256 * 128 * 2;
    unsigned short* wt1 = (unsigned short*)p; p += 256 * 128 * 2;
    unsigned short* wt2 = (unsigned short*)p; p += 64 * 128 * 2;
    int* rowp    = (int*)p;      p += ((size_t)(N + 1) * 4 + 255) / 256 * 256;
    int* binCnt  = (int*)p;      p += (NBIN * 4 + 255) / 256 * 256;
    int* binBase = (int*)p;      p += ((NBIN + 1) * 4 + 255) / 256 * 256;
    int* binCur  = (int*)p;      p += (NBIN * 4 + 255) / 256 * 256;
    unsigned* ebin = (unsigned*)p; p += (size_t)E * 4;
    int* csrc    = (int*)p;

    const int nchunks = (E + CHUNK - 1) / CHUNK;  // 196

    // ---- binned CSR build ----
    hipMemsetAsync(binCnt, 0, NBIN * 4, stream);
    bin_count<<<nchunks, 256, 0, stream>>>(dst, binCnt, E);
    bin_scan<<<1, 256, 0, stream>>>(binCnt, binBase, binCur, rowp, N, E);
    bin_scatter<<<nchunks, 256, 0, stream>>>(src, dst, binCur, ebin, E);
    csr_build<<<NBIN, 256, 0, stream>>>(ebin, binBase, rowp, csrc, N);

    // ---- bf16 conversions ----
    const int n4 = N * 128 / 4;
    convert_feat<<<(n4 + 255) / 256, 256, 0, stream>>>(feats, xb, n4);
    transpose_all<<<(73728 + 255) / 256, 256, 0, stream>>>(Ws0, Wd0, Ws1, Wd1, Ws2, Wd2, wt0, wt1, wt2);

    const int g256 = nch;
    const int g64  = (nch + 3) / 4;
    const int convGrid = 2048;  // 8192 persistent waves

    // ---- layer 0 ----
    gemm_dual2<256><<<g256, 256, 0, stream>>>(xb, wt0, bs0, bd0, fsb, fdb, N, nch);
    conv128<<<convGrid, 256, 0, stream>>>(fsb, fdb, a0, rowp, csrc, hb, N);
    // ---- layer 1 ----
    gemm_dual2<256><<<g256, 256, 0, stream>>>(hb, wt1, bs1, bd1, fsb, fdb, N, nch);
    conv128<<<convGrid, 256, 0, stream>>>(fsb, fdb, a1, rowp, csrc, hb, N);
    // ---- layer 2 ----
    gemm_dual2<64><<<g64, 256, 0, stream>>>(hb, wt2, bs2, bd2, fsb, fdb, N, nch);
    conv32<<<convGrid, 256, 0, stream>>>(fsb, fdb, a2, rowp, csrc, (float*)d_out, N);
}

// Round 7
// 292.386 us; speedup vs baseline: 2.0124x; 1.0594x over previous
//
#include <hip/hip_runtime.h>

typedef __attribute__((ext_vector_type(8))) short bf16x8;
typedef __attribute__((ext_vector_type(4))) float f32x4;

#define LOG2E 1.4426950408889634f

// CSR binning parameters: bins of 256 dst nodes
#define BINSH 8
#define NBIN 196        // ceil(50000/256)
#define CHUNK 4096      // edges per bin_scatter block
#define K4CAP 6144      // staged edges per bin in csr_build (avg 4096)

__device__ __forceinline__ unsigned bf_rn(float f) {
    unsigned u = __float_as_uint(f);
    u += 0x7fffu + ((u >> 16) & 1u);
    return u >> 16;
}
__device__ __forceinline__ float bf_lo(unsigned u) { return __uint_as_float(u << 16); }
__device__ __forceinline__ float bf_hi(unsigned u) { return __uint_as_float(u & 0xffff0000u); }

// DPP add helpers (VALU pipe, no DS)
template <int CTRL>
__device__ __forceinline__ float dpp_radd(float x) {
    int t = __builtin_amdgcn_update_dpp(0, __float_as_int(x), CTRL, 0xF, 0xF, true);
    return x + __int_as_float(t);
}
// sum across aligned 8-lane group (all 8 lanes get the sum):
// row_half_mirror, quad_perm[3,2,1,0], quad_perm[1,0,3,2]
__device__ __forceinline__ float sum8(float p) {
    p = dpp_radd<0x141>(p);
    p = dpp_radd<0x1B>(p);
    p = dpp_radd<0xB1>(p);
    return p;
}
// neighbor swap (lane ^ 1) via quad_perm [1,0,3,2]
__device__ __forceinline__ float dpp_swap1(float x) {
    return __int_as_float(__builtin_amdgcn_update_dpp(0, __float_as_int(x), 0xB1, 0xF, 0xF, true));
}

__device__ __forceinline__ float fast_exp2(float x) {
#if __has_builtin(__builtin_amdgcn_exp2f)
    return __builtin_amdgcn_exp2f(x);
#else
    return __expf(x * 0.6931471805599453f);
#endif
}

// ---------------------------------------------------------------------------
// Binned CSR build (2-pass radix on dst; ~40k atomics instead of 1.6M)
// ---------------------------------------------------------------------------

__global__ __launch_bounds__(256) void bin_count(const int* __restrict__ dst,
                                                 int* __restrict__ binCnt, int e) {
    __shared__ int hist[NBIN];
    for (int t = threadIdx.x; t < NBIN; t += 256) hist[t] = 0;
    __syncthreads();
    int base = blockIdx.x * CHUNK;
    int cnt = min(CHUNK, e - base);
    for (int j = threadIdx.x; j < cnt; j += 256)
        atomicAdd(&hist[dst[base + j] >> BINSH], 1);
    __syncthreads();
    for (int t = threadIdx.x; t < NBIN; t += 256)
        if (hist[t]) atomicAdd(&binCnt[t], hist[t]);
}

__global__ void bin_scan(const int* __restrict__ binCnt, int* __restrict__ binBase,
                         int* __restrict__ binCur, int* __restrict__ rowp, int n, int e) {
    int t = threadIdx.x;
    int v = (t < NBIN) ? binCnt[t] : 0;
    int lane = t & 63, w = t >> 6;
    int incl = v;
    for (int off = 1; off < 64; off <<= 1) {
        int tt = __shfl_up(incl, off);
        if (lane >= off) incl += tt;
    }
    __shared__ int wsum[4];
    if (lane == 63) wsum[w] = incl;
    __syncthreads();
    int wpre = 0;
    for (int i = 0; i < w; ++i) wpre += wsum[i];
    int excl = wpre + incl - v;
    if (t < NBIN) { binBase[t] = excl; binCur[t] = excl; }
    if (t == 0) { binBase[NBIN] = e; rowp[n] = e; }
}

__global__ __launch_bounds__(256) void bin_scatter(
    const int* __restrict__ src, const int* __restrict__ dst,
    int* __restrict__ binCur, unsigned* __restrict__ ebin, int e) {
    __shared__ int hist[NBIN];
    __shared__ int seg[NBIN];
    __shared__ int gbase[NBIN];
    __shared__ unsigned pack[CHUNK];
    for (int t = threadIdx.x; t < NBIN; t += 256) hist[t] = 0;
    __syncthreads();
    int base = blockIdx.x * CHUNK;
    int cnt = min(CHUNK, e - base);

    int myb[CHUNK / 256], myr[CHUNK / 256];
    unsigned myw[CHUNK / 256];
    int nmine = 0;
    for (int j = threadIdx.x; j < cnt; j += 256) {
        int d = dst[base + j], s = src[base + j];
        int b = d >> BINSH, dl = d & ((1 << BINSH) - 1);
        int r = atomicAdd(&hist[b], 1);
        myb[nmine] = b; myr[nmine] = r;
        myw[nmine] = ((unsigned)b << 24) | ((unsigned)dl << 16) | (unsigned)s;
        ++nmine;
    }
    __syncthreads();
    if (threadIdx.x == 0) {
        int acc = 0;
        for (int b2 = 0; b2 < NBIN; ++b2) { seg[b2] = acc; acc += hist[b2]; }
    }
    __syncthreads();
    for (int k = 0; k < nmine; ++k)
        pack[seg[myb[k]] + myr[k]] = myw[k];
    __syncthreads();
    if (threadIdx.x < NBIN && hist[threadIdx.x])
        gbase[threadIdx.x] = atomicAdd(&binCur[threadIdx.x], hist[threadIdx.x]);
    __syncthreads();
    for (int j = threadIdx.x; j < cnt; j += 256) {
        unsigned wv = pack[j];
        int b = wv >> 24;
        ebin[gbase[b] + (j - seg[b])] = wv;
    }
}

__global__ __launch_bounds__(256) void csr_build(
    const unsigned* __restrict__ ebin, const int* __restrict__ binBase,
    int* __restrict__ rowp, int* __restrict__ csrc, int n) {
    __shared__ int hist[256];
    __shared__ int seg[256];
    __shared__ unsigned stage[K4CAP];
    int b = blockIdx.x;
    int e0 = binBase[b], e1 = binBase[b + 1];
    int n0 = b << BINSH;
    int nn = min(256, n - n0);
    for (int t = threadIdx.x; t < 256; t += 256) hist[t] = 0;
    __syncthreads();
    for (int i = e0 + threadIdx.x; i < e1; i += 256) {
        unsigned wv = ebin[i];
        atomicAdd(&hist[(wv >> 16) & 255], 1);
        int off = i - e0;
        if (off < K4CAP) stage[off] = wv;
    }
    __syncthreads();
    if (threadIdx.x < 64) {
        int l = threadIdx.x;
        int s = 0, loc[4];
#pragma unroll
        for (int k = 0; k < 4; ++k) { loc[k] = s; s += hist[l * 4 + k]; }
        int incl = s;
        for (int off = 1; off < 64; off <<= 1) {
            int tt = __shfl_up(incl, off);
            if (l >= off) incl += tt;
        }
        int excl = incl - s;
#pragma unroll
        for (int k = 0; k < 4; ++k) seg[l * 4 + k] = excl + loc[k];
    }
    __syncthreads();
    for (int t = threadIdx.x; t < nn; t += 256) rowp[n0 + t] = e0 + seg[t];
    for (int t = threadIdx.x; t < 256; t += 256) hist[t] = seg[t];
    __syncthreads();
    for (int i = e0 + threadIdx.x; i < e1; i += 256) {
        int off = i - e0;
        unsigned wv = (off < K4CAP) ? stage[off] : ebin[i];
        int dl = (wv >> 16) & 255;
        int pos = e0 + atomicAdd(&hist[dl], 1);
        csrc[pos] = (int)(wv & 0xFFFFu);
    }
}

// ---------------------------------------------------------------------------
// fp32 -> bf16 conversions (once per launch)
// ---------------------------------------------------------------------------

__global__ void convert_feat(const float* __restrict__ x, unsigned short* __restrict__ o, int n4) {
    int i = blockIdx.x * blockDim.x + threadIdx.x;
    if (i < n4) {
        float4 v = *(const float4*)(x + (size_t)i * 4);
        ushort4 r;
        r.x = (unsigned short)bf_rn(v.x); r.y = (unsigned short)bf_rn(v.y);
        r.z = (unsigned short)bf_rn(v.z); r.w = (unsigned short)bf_rn(v.w);
        *(ushort4*)(o + (size_t)i * 4) = r;
    }
}

__global__ void transpose_all(
    const float* __restrict__ Ws0, const float* __restrict__ Wd0,
    const float* __restrict__ Ws1, const float* __restrict__ Wd1,
    const float* __restrict__ Ws2, const float* __restrict__ Wd2,
    unsigned short* __restrict__ wt0, unsigned short* __restrict__ wt1,
    unsigned short* __restrict__ wt2) {
    int gid = blockIdx.x * blockDim.x + threadIdx.x;
    if (gid < 65536) {
        int l = gid >> 15, loc = gid & 32767;
        int c = loc >> 7, k = loc & 127;
        const float* W = (c < 128) ? (l ? Ws1 : Ws0) : (l ? Wd1 : Wd0);
        int cc = c & 127;
        float v = W[(size_t)k * 128 + cc];
        (l ? wt1 : wt0)[loc] = (unsigned short)bf_rn(v);
    } else if (gid < 65536 + 8192) {
        int loc = gid - 65536;
        int c = loc >> 7, k = loc & 127;
        const float* W = (c < 32) ? Ws2 : Wd2;
        int cc = (c < 32) ? c : c - 32;
        float v = W[(size_t)k * 32 + cc];
        wt2[loc] = (unsigned short)bf_rn(v);
    }
}

// ---------------------------------------------------------------------------
// Zero-LDS MFMA dual GEMM: [fs|fd] = x @ [Ws|Wd] + [bs|bd].
// ---------------------------------------------------------------------------

template <int COLS2>
__global__ __launch_bounds__(256) void gemm_dual2(
    const unsigned short* __restrict__ xb, const unsigned short* __restrict__ wt,
    const float* __restrict__ bs, const float* __restrict__ bd,
    unsigned short* __restrict__ fs, unsigned short* __restrict__ fd,
    int n, int nch) {
    constexpr int C  = COLS2 / 2;
    constexpr int NC = COLS2 / 64;

    const int lane = threadIdx.x & 63;
    const int m = lane & 15, quad = lane >> 4;
    const int gwid = blockIdx.x * 4 + (threadIdx.x >> 6);
    const int nwaves = gridDim.x * 4;
    const int cs = gwid % NC;
    const int cstride = nwaves / NC;

    float biasv[4];
#pragma unroll
    for (int ct = 0; ct < 4; ++ct) {
        int col = cs * 64 + ct * 16 + m;
        biasv[ct] = (col < C) ? bs[col] : bd[col - C];
    }

    for (int chunk = gwid / NC; chunk < nch; chunk += cstride) {
        const size_t r0 = (size_t)chunk * 64;

        f32x4 acc[4][4];
#pragma unroll
        for (int rt = 0; rt < 4; ++rt)
#pragma unroll
            for (int ct = 0; ct < 4; ++ct) acc[rt][ct] = (f32x4){0.f, 0.f, 0.f, 0.f};

#pragma unroll
        for (int ks = 0; ks < 4; ++ks) {
            const int ko = ks * 32 + quad * 8;
            bf16x8 a[4], b[4];
#pragma unroll
            for (int rt = 0; rt < 4; ++rt)
                a[rt] = *(const bf16x8*)(xb + (r0 + rt * 16 + m) * 128 + ko);
#pragma unroll
            for (int ct = 0; ct < 4; ++ct)
                b[ct] = *(const bf16x8*)(wt + (size_t)(cs * 64 + ct * 16 + m) * 128 + ko);
#pragma unroll
            for (int rt = 0; rt < 4; ++rt)
#pragma unroll
                for (int ct = 0; ct < 4; ++ct)
                    acc[rt][ct] = __builtin_amdgcn_mfma_f32_16x16x32_bf16(a[rt], b[ct], acc[rt][ct], 0, 0, 0);
        }

        const int odd = m & 1;
#pragma unroll
        for (int ct = 0; ct < 4; ++ct) {
            int colE = cs * 64 + ct * 16 + (m & ~1);
            unsigned short* ptr = (colE < C) ? fs : fd;
            int cc = (colE < C) ? colE : colE - C;
#pragma unroll
            for (int rt = 0; rt < 4; ++rt) {
                float v0 = acc[rt][ct][0] + biasv[ct];
                float v1 = acc[rt][ct][1] + biasv[ct];
                float v2 = acc[rt][ct][2] + biasv[ct];
                float v3 = acc[rt][ct][3] + biasv[ct];
                float s0 = dpp_swap1(v0), s1 = dpp_swap1(v1);
                float s2 = dpp_swap1(v2), s3 = dpp_swap1(v3);
                float aLo = odd ? s2 : v0, aHi = odd ? v2 : s0;
                float bLo = odd ? s3 : v1, bHi = odd ? v3 : s1;
                int rowA = (int)r0 + rt * 16 + quad * 4 + (odd ? 2 : 0);
                unsigned pa = (bf_rn(aHi) << 16) | bf_rn(aLo);
                unsigned pb = (bf_rn(bHi) << 16) | bf_rn(bLo);
                if (rowA < n)     *(unsigned*)(ptr + (size_t)rowA * C + cc)       = pa;
                if (rowA + 1 < n) *(unsigned*)(ptr + ((size_t)rowA + 1) * C + cc) = pb;
            }
        }
    }
}

// ---------------------------------------------------------------------------
// GATv2 aggregation. conv128: 2 edges/wave (32 lanes = 4 feats/lane each);
// conv32: 8 edges/wave (8 lanes = 4 feats/lane each). 8-lane DPP reduction.
// ---------------------------------------------------------------------------

// per-edge math: 4 feats/lane, 8-lane head groups. mval masks ex (1.0 folds).
#define EDGE_BODY(u, mval)                                          \
    do {                                                            \
        float x0 = bf_lo((u).x), x1 = bf_hi((u).x);                 \
        float x2 = bf_lo((u).y), x3 = bf_hi((u).y);                 \
        float t0 = x0 + fd0, t1 = x1 + fd1;                         \
        float t2 = x2 + fd2, t3 = x3 + fd3;                         \
        float p = a060 * t0;                                        \
        p = fmaf(a040, fabsf(t0), p);                               \
        p = fmaf(a061, t1, p); p = fmaf(a041, fabsf(t1), p);        \
        p = fmaf(a062, t2, p); p = fmaf(a042, fabsf(t2), p);        \
        p = fmaf(a063, t3, p); p = fmaf(a043, fabsf(t3), p);        \
        p = sum8(p);                                                \
        float ex = fast_exp2(p) * (mval);                           \
        denom += ex;                                                \
        acc0 = fmaf(ex, x0, acc0); acc1 = fmaf(ex, x1, acc1);       \
        acc2 = fmaf(ex, x2, acc2); acc3 = fmaf(ex, x3, acc3);       \
    } while (0)

__global__ __launch_bounds__(256) void conv128(
    const unsigned short* __restrict__ fs, const unsigned short* __restrict__ fd,
    const float* __restrict__ attn, const int* __restrict__ rowp,
    const int* __restrict__ csrc, unsigned short* __restrict__ out, int n) {
    const int nwaves = gridDim.x * 4;
    const int wid0 = blockIdx.x * 4 + (threadIdx.x >> 6);
    const int lane = threadIdx.x & 63;
    const int half = lane >> 5;     // which edge of the pair
    const int q = lane & 31;        // 4-feat chunk [0,32); head = q>>3

    float4 av = *(const float4*)(attn + q * 4);
    const float a060 = av.x * 0.6f * LOG2E, a040 = av.x * 0.4f * LOG2E;
    const float a061 = av.y * 0.6f * LOG2E, a041 = av.y * 0.4f * LOG2E;
    const float a062 = av.z * 0.6f * LOG2E, a042 = av.z * 0.4f * LOG2E;
    const float a063 = av.w * 0.6f * LOG2E, a043 = av.w * 0.4f * LOG2E;

    for (int wid = wid0; wid < n; wid += nwaves) {
        uint2 ud = *(const uint2*)(fd + (size_t)wid * 128 + q * 4);
        float fd0 = bf_lo(ud.x), fd1 = bf_hi(ud.x);
        float fd2 = bf_lo(ud.y), fd3 = bf_hi(ud.y);
        int rs = rowp[wid], re = rowp[wid + 1];
        float acc0 = 0.f, acc1 = 0.f, acc2 = 0.f, acc3 = 0.f, denom = 0.f;

        int i = rs;
        // two pairs (4 edges) in flight
        for (; i + 3 < re; i += 4) {
            int sA = csrc[i + half];
            int sB = csrc[i + 2 + half];
            uint2 uA = *(const uint2*)(fs + ((size_t)sA << 7) + q * 4);
            uint2 uB = *(const uint2*)(fs + ((size_t)sB << 7) + q * 4);
            EDGE_BODY(uA, 1.0f);
            EDGE_BODY(uB, 1.0f);
        }
        for (; i + 1 < re; i += 2) {
            int s = csrc[i + half];
            uint2 u = *(const uint2*)(fs + ((size_t)s << 7) + q * 4);
            EDGE_BODY(u, 1.0f);
        }
        if (i < re) {  // odd tail: both halves load same edge, half 1 masked
            int s = csrc[i];
            uint2 u = *(const uint2*)(fs + ((size_t)s << 7) + q * 4);
            float mval = half ? 0.f : 1.f;
            EDGE_BODY(u, mval);
        }
        // combine the two halves
        acc0 += __shfl_xor(acc0, 32); acc1 += __shfl_xor(acc1, 32);
        acc2 += __shfl_xor(acc2, 32); acc3 += __shfl_xor(acc3, 32);
        denom += __shfl_xor(denom, 32);
        float inv = (re > rs) ? 1.f / denom : 0.f;
        float r0 = fmaxf(acc0 * inv, 0.f), r1 = fmaxf(acc1 * inv, 0.f);
        float r2 = fmaxf(acc2 * inv, 0.f), r3 = fmaxf(acc3 * inv, 0.f);
        if (half == 0) {
            uint2 o;
            o.x = (bf_rn(r1) << 16) | bf_rn(r0);
            o.y = (bf_rn(r3) << 16) | bf_rn(r2);
            ((uint2*)(out + (size_t)wid * 128))[q] = o;
        }
    }
}

// Layer 2: 1 head x 32 feats; 8 edges/wave, 8 lanes (4 feats each) per edge.
__global__ __launch_bounds__(256) void conv32(
    const unsigned short* __restrict__ fs, const unsigned short* __restrict__ fd,
    const float* __restrict__ attn, const int* __restrict__ rowp,
    const int* __restrict__ csrc, float* __restrict__ out, int n) {
    const int nwaves = gridDim.x * 4;
    const int wid0 = blockIdx.x * 4 + (threadIdx.x >> 6);
    const int lane = threadIdx.x & 63;
    const int g = lane >> 3;    // edge slot [0,8)
    const int c = lane & 7;     // 4-feat chunk [0,8)

    float4 av = *(const float4*)(attn + c * 4);
    const float a060 = av.x * 0.6f * LOG2E, a040 = av.x * 0.4f * LOG2E;
    const float a061 = av.y * 0.6f * LOG2E, a041 = av.y * 0.4f * LOG2E;
    const float a062 = av.z * 0.6f * LOG2E, a042 = av.z * 0.4f * LOG2E;
    const float a063 = av.w * 0.6f * LOG2E, a043 = av.w * 0.4f * LOG2E;

    for (int wid = wid0; wid < n; wid += nwaves) {
        uint2 ud = *(const uint2*)(fd + (size_t)wid * 32 + c * 4);
        float fd0 = bf_lo(ud.x), fd1 = bf_hi(ud.x);
        float fd2 = bf_lo(ud.y), fd3 = bf_hi(ud.y);
        int rs = rowp[wid], re = rowp[wid + 1];
        float acc0 = 0.f, acc1 = 0.f, acc2 = 0.f, acc3 = 0.f, denom = 0.f;

        int i = rs;
        for (; i + 7 < re; i += 8) {
            int s = csrc[i + g];
            uint2 u = *(const uint2*)(fs + ((size_t)s << 5) + c * 4);
            EDGE_BODY(u, 1.0f);
        }
        if (i < re) {  // masked tail group
            int idx = i + g;
            int s = csrc[min(idx, re - 1)];
            uint2 u = *(const uint2*)(fs + ((size_t)s << 5) + c * 4);
            float mval = (idx < re) ? 1.f : 0.f;
            EDGE_BODY(u, mval);
        }
        // combine the 8 edge slots: rot8-within-16 (DPP), then xor 16, 32
        acc0 = dpp_radd<0x128>(acc0); acc1 = dpp_radd<0x128>(acc1);
        acc2 = dpp_radd<0x128>(acc2); acc3 = dpp_radd<0x128>(acc3);
        denom = dpp_radd<0x128>(denom);
        acc0 += __shfl_xor(acc0, 16); acc1 += __shfl_xor(acc1, 16);
        acc2 += __shfl_xor(acc2, 16); acc3 += __shfl_xor(acc3, 16);
        denom += __shfl_xor(denom, 16);
        acc0 += __shfl_xor(acc0, 32); acc1 += __shfl_xor(acc1, 32);
        acc2 += __shfl_xor(acc2, 32); acc3 += __shfl_xor(acc3, 32);
        denom += __shfl_xor(denom, 32);
        float inv = (re > rs) ? 1.f / denom : 0.f;
        if (lane < 8) {
            float4 o;
            o.x = acc0 * inv; o.y = acc1 * inv;
            o.z = acc2 * inv; o.w = acc3 * inv;
            *(float4*)(out + (size_t)wid * 32 + c * 4) = o;
        }
    }
}

// ---------------------------------------------------------------------------

extern "C" void kernel_launch(void* const* d_in, const int* in_sizes, int n_in,
                              void* d_out, int out_size, void* d_ws, size_t ws_size,
                              hipStream_t stream) {
    const float* feats = (const float*)d_in[0];
    const int*   src   = (const int*)d_in[1];
    const int*   dst   = (const int*)d_in[2];
    const float* Ws0 = (const float*)d_in[3],  *bs0 = (const float*)d_in[4];
    const float* Wd0 = (const float*)d_in[5],  *bd0 = (const float*)d_in[6];
    const float* a0  = (const float*)d_in[7];
    const float* Ws1 = (const float*)d_in[8],  *bs1 = (const float*)d_in[9];
    const float* Wd1 = (const float*)d_in[10], *bd1 = (const float*)d_in[11];
    const float* a1  = (const float*)d_in[12];
    const float* Ws2 = (const float*)d_in[13], *bs2 = (const float*)d_in[14];
    const float* Wd2 = (const float*)d_in[15], *bd2 = (const float*)d_in[16];
    const float* a2  = (const float*)d_in[17];

    const int N = in_sizes[0] / 128;  // 50000
    const int E = in_sizes[1];        // 800000
    const int nch = (N + 63) / 64;
    const int NPAD = nch * 64;

    char* ws = (char*)d_ws;
    const size_t featB = (size_t)NPAD * 128 * 2;
    unsigned short* xb  = (unsigned short*)(ws);
    unsigned short* hb  = (unsigned short*)(ws + featB);
    unsigned short* fsb = (unsigned short*)(ws + 2 * featB);
    unsigned short* fdb = (unsigned short*)(ws + 3 * featB);
    char* p = ws + 4 * featB;
    unsigned short* wt0 = (unsigned short*)p; p += 256 * 128 * 2;
    unsigned short* wt1 = (unsigned short*)p; p += 256 * 128 * 2;
    unsigned short* wt2 = (unsigned short*)p; p += 64 * 128 * 2;
    int* rowp    = (int*)p;      p += ((size_t)(N + 1) * 4 + 255) / 256 * 256;
    int* binCnt  = (int*)p;      p += (NBIN * 4 + 255) / 256 * 256;
    int* binBase = (int*)p;      p += ((NBIN + 1) * 4 + 255) / 256 * 256;
    int* binCur  = (int*)p;      p += (NBIN * 4 + 255) / 256 * 256;
    unsigned* ebin = (unsigned*)p; p += (size_t)E * 4;
    int* csrc    = (int*)p;

    const int nchunks = (E + CHUNK - 1) / CHUNK;

    // ---- binned CSR build ----
    hipMemsetAsync(binCnt, 0, NBIN * 4, stream);
    bin_count<<<nchunks, 256, 0, stream>>>(dst, binCnt, E);
    bin_scan<<<1, 256, 0, stream>>>(binCnt, binBase, binCur, rowp, N, E);
    bin_scatter<<<nchunks, 256, 0, stream>>>(src, dst, binCur, ebin, E);
    csr_build<<<NBIN, 256, 0, stream>>>(ebin, binBase, rowp, csrc, N);

    // ---- bf16 conversions ----
    const int n4 = N * 128 / 4;
    convert_feat<<<(n4 + 255) / 256, 256, 0, stream>>>(feats, xb, n4);
    transpose_all<<<(73728 + 255) / 256, 256, 0, stream>>>(Ws0, Wd0, Ws1, Wd1, Ws2, Wd2, wt0, wt1, wt2);

    const int g256 = nch;
    const int g64  = (nch + 3) / 4;
    const int convGrid = 2048;  // 8192 persistent waves

    // ---- layer 0 ----
    gemm_dual2<256><<<g256, 256, 0, stream>>>(xb, wt0, bs0, bd0, fsb, fdb, N, nch);
    conv128<<<convGrid, 256, 0, stream>>>(fsb, fdb, a0, rowp, csrc, hb, N);
    // ---- layer 1 ----
    gemm_dual2<256><<<g256, 256, 0, stream>>>(hb, wt1, bs1, bd1, fsb, fdb, N, nch);
    conv128<<<convGrid, 256, 0, stream>>>(fsb, fdb, a1, rowp, csrc, hb, N);
    // ---- layer 2 ----
    gemm_dual2<64><<<g64, 256, 0, stream>>>(hb, wt2, bs2, bd2, fsb, fdb, N, nch);
    conv32<<<convGrid, 256, 0, stream>>>(fsb, fdb, a2, rowp, csrc, (float*)d_out, N);
}